// Round 1
// baseline (6342.799 us; speedup 1.0000x reference)
//
#include <hip/hip_runtime.h>

#define DD 64

// ---------------- prep: fold g @ W1[g-rows] into effective layer-1 biases ----------------
__global__ void prep_bias_kernel(const float* __restrict__ g,
                                 const float* __restrict__ We1, const float* __restrict__ be1,
                                 const float* __restrict__ Wn1, const float* __restrict__ bn1,
                                 float* __restrict__ be1e, float* __restrict__ bn1e) {
    int j = threadIdx.x;  // 64 threads
    float a = be1[j];
    float b = bn1[j];
    for (int k = 0; k < DD; ++k) {
        float gk = g[k];
        a = fmaf(gk, We1[(192 + k) * DD + j], a);  // g rows of We1: 192..255
        b = fmaf(gk, Wn1[(128 + k) * DD + j], b);  // g rows of Wn1: 128..191
    }
    be1e[j] = a;
    bn1e[j] = b;
}

// ---------------- edge update: 64 edges x 64 outputs per 256-thread block ----------------
__global__ __launch_bounds__(256) void edge_kernel(
    const float* __restrict__ edges_in, const float* __restrict__ nodes_in,
    const int* __restrict__ senders, const int* __restrict__ receivers,
    const float* __restrict__ W1, const float* __restrict__ b1e,
    const float* __restrict__ W2, const float* __restrict__ b2,
    float* __restrict__ edges_out, float* __restrict__ received,
    float* __restrict__ agg_e, int E)
{
    __shared__ __align__(16) float AT[64 * 68];  // x^T chunk: AT[k][e], reused for h^T
    __shared__ float PS[16 * 65];
    __shared__ int sidx[64];
    __shared__ int ridx[64];

    const int t  = threadIdx.x;
    const int eq = t >> 4, oq = t & 15;
    const int e0 = eq << 2, j0 = oq << 2;
    const int le = t >> 2, lq = t & 3;       // loader: row le, quarter lq
    const int eb = blockIdx.x << 6;
    const int evalid = min(64, E - eb);

    if (t < 64) sidx[t] = (t < evalid) ? senders[eb + t] : 0;
    else if (t < 128) ridx[t - 64] = (t - 64 < evalid) ? receivers[eb + t - 64] : 0;

    float4 bv = *(const float4*)(b1e + j0);
    float acc[4][4];
#pragma unroll
    for (int a = 0; a < 4; ++a) { acc[a][0] = bv.x; acc[a][1] = bv.y; acc[a][2] = bv.z; acc[a][3] = bv.w; }

    // GEMM1: k = 192 in three 64-chunks: own edge row, sender gather, receiver gather
    for (int c = 0; c < 3; ++c) {
        __syncthreads();
        if (le < evalid) {
            const float* src;
            if (c == 0)      src = edges_in + (size_t)(eb + le) * DD;
            else if (c == 1) src = nodes_in + (size_t)sidx[le] * DD;
            else             src = nodes_in + (size_t)ridx[le] * DD;
#pragma unroll
            for (int i = 0; i < 4; ++i) {
                float4 v = *(const float4*)(src + lq * 16 + i * 4);
                int k = lq * 16 + i * 4;
                AT[(k + 0) * 68 + le] = v.x;
                AT[(k + 1) * 68 + le] = v.y;
                AT[(k + 2) * 68 + le] = v.z;
                AT[(k + 3) * 68 + le] = v.w;
            }
        } else {
#pragma unroll
            for (int i = 0; i < 16; ++i) AT[(lq * 16 + i) * 68 + le] = 0.f;
        }
        __syncthreads();
        const float* wb = W1 + c * (DD * DD);
#pragma unroll 4
        for (int kk = 0; kk < DD; ++kk) {
            float4 av = *(const float4*)&AT[kk * 68 + e0];
            float4 wv = *(const float4*)(wb + kk * DD + j0);
            float A4[4] = {av.x, av.y, av.z, av.w};
            float W4[4] = {wv.x, wv.y, wv.z, wv.w};
#pragma unroll
            for (int a = 0; a < 4; ++a)
#pragma unroll
                for (int b = 0; b < 4; ++b)
                    acc[a][b] = fmaf(A4[a], W4[b], acc[a][b]);
        }
    }

    // ReLU + write h^T into AT
    __syncthreads();
#pragma unroll
    for (int b = 0; b < 4; ++b)
#pragma unroll
        for (int a = 0; a < 4; ++a)
            AT[(j0 + b) * 68 + (e0 + a)] = fmaxf(acc[a][b], 0.f);
    __syncthreads();

    // GEMM2: k = 64
    float4 b2v = *(const float4*)(b2 + j0);
    float acc2[4][4];
#pragma unroll
    for (int a = 0; a < 4; ++a) { acc2[a][0] = b2v.x; acc2[a][1] = b2v.y; acc2[a][2] = b2v.z; acc2[a][3] = b2v.w; }
#pragma unroll 4
    for (int kk = 0; kk < DD; ++kk) {
        float4 av = *(const float4*)&AT[kk * 68 + e0];
        float4 wv = *(const float4*)(W2 + kk * DD + j0);
        float A4[4] = {av.x, av.y, av.z, av.w};
        float W4[4] = {wv.x, wv.y, wv.z, wv.w};
#pragma unroll
        for (int a = 0; a < 4; ++a)
#pragma unroll
            for (int b = 0; b < 4; ++b)
                acc2[a][b] = fmaf(A4[a], W4[b], acc2[a][b]);
    }

    // store new edges + scatter into received + block-partial agg_e
#pragma unroll
    for (int a = 0; a < 4; ++a) {
        if (e0 + a < evalid) {
            float4 o; o.x = acc2[a][0]; o.y = acc2[a][1]; o.z = acc2[a][2]; o.w = acc2[a][3];
            *(float4*)(edges_out + (size_t)(eb + e0 + a) * DD + j0) = o;
            float* dst = received + (size_t)ridx[e0 + a] * DD + j0;
            atomicAdd(dst + 0, acc2[a][0]);
            atomicAdd(dst + 1, acc2[a][1]);
            atomicAdd(dst + 2, acc2[a][2]);
            atomicAdd(dst + 3, acc2[a][3]);
        }
    }
#pragma unroll
    for (int b = 0; b < 4; ++b) {
        float s = 0.f;
#pragma unroll
        for (int a = 0; a < 4; ++a)
            if (e0 + a < evalid) s += acc2[a][b];
        PS[eq * 65 + j0 + b] = s;
    }
    __syncthreads();
    if (t < 64) {
        float s = 0.f;
#pragma unroll
        for (int q = 0; q < 16; ++q) s += PS[q * 65 + t];
        atomicAdd(agg_e + t, s);
    }
}

// ---------------- node update: 64 nodes x 64 outputs per 256-thread block ----------------
__global__ __launch_bounds__(256) void node_kernel(
    const float* __restrict__ nodes_in, const float* __restrict__ received,
    const float* __restrict__ W1, const float* __restrict__ b1e,
    const float* __restrict__ W2, const float* __restrict__ b2,
    float* __restrict__ nodes_out, float* __restrict__ agg_n, int N)
{
    __shared__ __align__(16) float AT[64 * 68];
    __shared__ float PS[16 * 65];

    const int t  = threadIdx.x;
    const int eq = t >> 4, oq = t & 15;
    const int e0 = eq << 2, j0 = oq << 2;
    const int le = t >> 2, lq = t & 3;
    const int nb = blockIdx.x << 6;
    const int nvalid = min(64, N - nb);

    float4 bv = *(const float4*)(b1e + j0);
    float acc[4][4];
#pragma unroll
    for (int a = 0; a < 4; ++a) { acc[a][0] = bv.x; acc[a][1] = bv.y; acc[a][2] = bv.z; acc[a][3] = bv.w; }

    // GEMM1: k = 128 in two chunks: own node row, received row
    for (int c = 0; c < 2; ++c) {
        __syncthreads();
        if (le < nvalid) {
            const float* src = (c == 0 ? nodes_in : received) + (size_t)(nb + le) * DD;
#pragma unroll
            for (int i = 0; i < 4; ++i) {
                float4 v = *(const float4*)(src + lq * 16 + i * 4);
                int k = lq * 16 + i * 4;
                AT[(k + 0) * 68 + le] = v.x;
                AT[(k + 1) * 68 + le] = v.y;
                AT[(k + 2) * 68 + le] = v.z;
                AT[(k + 3) * 68 + le] = v.w;
            }
        } else {
#pragma unroll
            for (int i = 0; i < 16; ++i) AT[(lq * 16 + i) * 68 + le] = 0.f;
        }
        __syncthreads();
        const float* wb = W1 + c * (DD * DD);
#pragma unroll 4
        for (int kk = 0; kk < DD; ++kk) {
            float4 av = *(const float4*)&AT[kk * 68 + e0];
            float4 wv = *(const float4*)(wb + kk * DD + j0);
            float A4[4] = {av.x, av.y, av.z, av.w};
            float W4[4] = {wv.x, wv.y, wv.z, wv.w};
#pragma unroll
            for (int a = 0; a < 4; ++a)
#pragma unroll
                for (int b = 0; b < 4; ++b)
                    acc[a][b] = fmaf(A4[a], W4[b], acc[a][b]);
        }
    }

    __syncthreads();
#pragma unroll
    for (int b = 0; b < 4; ++b)
#pragma unroll
        for (int a = 0; a < 4; ++a)
            AT[(j0 + b) * 68 + (e0 + a)] = fmaxf(acc[a][b], 0.f);
    __syncthreads();

    float4 b2v = *(const float4*)(b2 + j0);
    float acc2[4][4];
#pragma unroll
    for (int a = 0; a < 4; ++a) { acc2[a][0] = b2v.x; acc2[a][1] = b2v.y; acc2[a][2] = b2v.z; acc2[a][3] = b2v.w; }
#pragma unroll 4
    for (int kk = 0; kk < DD; ++kk) {
        float4 av = *(const float4*)&AT[kk * 68 + e0];
        float4 wv = *(const float4*)(W2 + kk * DD + j0);
        float A4[4] = {av.x, av.y, av.z, av.w};
        float W4[4] = {wv.x, wv.y, wv.z, wv.w};
#pragma unroll
        for (int a = 0; a < 4; ++a)
#pragma unroll
            for (int b = 0; b < 4; ++b)
                acc2[a][b] = fmaf(A4[a], W4[b], acc2[a][b]);
    }

#pragma unroll
    for (int a = 0; a < 4; ++a) {
        if (e0 + a < nvalid) {
            float4 o; o.x = acc2[a][0]; o.y = acc2[a][1]; o.z = acc2[a][2]; o.w = acc2[a][3];
            *(float4*)(nodes_out + (size_t)(nb + e0 + a) * DD + j0) = o;
        }
    }
#pragma unroll
    for (int b = 0; b < 4; ++b) {
        float s = 0.f;
#pragma unroll
        for (int a = 0; a < 4; ++a)
            if (e0 + a < nvalid) s += acc2[a][b];
        PS[eq * 65 + j0 + b] = s;
    }
    __syncthreads();
    if (t < 64) {
        float s = 0.f;
#pragma unroll
        for (int q = 0; q < 16; ++q) s += PS[q * 65 + t];
        atomicAdd(agg_n + t, s);
    }
}

// ---------------- global update (tiny) ----------------
__global__ void global_kernel(const float* __restrict__ agg_n, const float* __restrict__ agg_e,
                              const float* __restrict__ g_in,
                              const float* __restrict__ Wg1, const float* __restrict__ bg1,
                              const float* __restrict__ Wg2, const float* __restrict__ bg2,
                              float* __restrict__ g_out)
{
    __shared__ float h[64];
    int j = threadIdx.x;  // 64 threads
    float a = bg1[j];
    for (int k = 0; k < DD; ++k) a = fmaf(agg_n[k], Wg1[k * DD + j], a);
    for (int k = 0; k < DD; ++k) a = fmaf(agg_e[k], Wg1[(64 + k) * DD + j], a);
    for (int k = 0; k < DD; ++k) a = fmaf(g_in[k],  Wg1[(128 + k) * DD + j], a);
    h[j] = fmaxf(a, 0.f);
    __syncthreads();
    float o = bg2[j];
    for (int k = 0; k < DD; ++k) o = fmaf(h[k], Wg2[k * DD + j], o);
    g_out[j] = o;
}

extern "C" void kernel_launch(void* const* d_in, const int* in_sizes, int n_in,
                              void* d_out, int out_size, void* d_ws, size_t ws_size,
                              hipStream_t stream) {
    const float* nodes0 = (const float*)d_in[0];
    const float* edges0 = (const float*)d_in[1];
    const float* g0     = (const float*)d_in[2];
    const int* senders   = (const int*)d_in[3];
    const int* receivers = (const int*)d_in[4];
    const float* We1 = (const float*)d_in[5];
    const float* be1 = (const float*)d_in[6];
    const float* We2 = (const float*)d_in[7];
    const float* be2 = (const float*)d_in[8];
    const float* Wn1 = (const float*)d_in[9];
    const float* bn1 = (const float*)d_in[10];
    const float* Wn2 = (const float*)d_in[11];
    const float* bn2 = (const float*)d_in[12];
    const float* Wg1 = (const float*)d_in[13];
    const float* bg1 = (const float*)d_in[14];
    const float* Wg2 = (const float*)d_in[15];
    const float* bg2 = (const float*)d_in[16];

    const int N = in_sizes[0] / DD;
    const int E = in_sizes[1] / DD;

    float* out_nodes = (float*)d_out;
    float* out_edges = out_nodes + (size_t)N * DD;
    float* out_g     = out_edges + (size_t)E * DD;

    float* ws = (float*)d_ws;
    float* received = ws;                         // N*64
    float* agg_n = received + (size_t)N * DD;     // 64
    float* agg_e = agg_n + 64;                    // 64
    float* b1e   = agg_n + 128;                   // 64
    float* b1n   = agg_n + 192;                   // 64
    float* g1    = agg_n + 256;                   // 64
    float* g2    = agg_n + 320;                   // 64

    const int eblocks = (E + 63) / 64;
    const int nblocks = (N + 63) / 64;

    for (int s = 0; s < 3; ++s) {
        const float* nsrc = (s == 0) ? nodes0 : out_nodes;
        const float* esrc = (s == 0) ? edges0 : out_edges;
        const float* gin  = (s == 0) ? g0 : ((s == 1) ? g1 : g2);
        float* gout       = (s == 2) ? out_g : ((s == 0) ? g1 : g2);

        hipMemsetAsync(received, 0, ((size_t)N * DD + 128) * sizeof(float), stream);
        prep_bias_kernel<<<1, 64, 0, stream>>>(gin, We1, be1, Wn1, bn1, b1e, b1n);
        edge_kernel<<<eblocks, 256, 0, stream>>>(esrc, nsrc, senders, receivers,
                                                 We1, b1e, We2, be2,
                                                 out_edges, received, agg_e, E);
        node_kernel<<<nblocks, 256, 0, stream>>>(nsrc, received, Wn1, b1n, Wn2, bn2,
                                                 out_nodes, agg_n, N);
        global_kernel<<<1, 64, 0, stream>>>(agg_n, agg_e, gin, Wg1, bg1, Wg2, bg2, gout);
    }
}

// Round 2
// 3858.161 us; speedup vs baseline: 1.6440x; 1.6440x over previous
//
#include <hip/hip_runtime.h>

#define DD 64

// ---------------- CSR build (receivers constant across steps; built once per launch) ----
__global__ void zero_counts_kernel(int* __restrict__ counts, int N) {
    int i = blockIdx.x * blockDim.x + threadIdx.x;
    if (i < N) counts[i] = 0;
}

__global__ void hist_kernel(const int* __restrict__ recv, int* __restrict__ counts, int E) {
    int i = blockIdx.x * blockDim.x + threadIdx.x;
    if (i < E) atomicAdd(&counts[recv[i]], 1);
}

// single-block scan, 1024 threads, 4 elements/thread per chunk
__global__ __launch_bounds__(1024) void scan_kernel(const int* __restrict__ counts,
                                                    int* __restrict__ offs,
                                                    int* __restrict__ cursor, int N) {
    __shared__ int sm[1024];
    __shared__ int carryS;
    int t = threadIdx.x;
    if (t == 0) carryS = 0;
    __syncthreads();
    for (int base = 0; base < N; base += 4096) {
        int idx = base + t * 4;
        int x0 = (idx + 0 < N) ? counts[idx + 0] : 0;
        int x1 = (idx + 1 < N) ? counts[idx + 1] : 0;
        int x2 = (idx + 2 < N) ? counts[idx + 2] : 0;
        int x3 = (idx + 3 < N) ? counts[idx + 3] : 0;
        int s1 = x0 + x1, s2 = s1 + x2, s3 = s2 + x3;
        sm[t] = s3;
        __syncthreads();
        for (int d = 1; d < 1024; d <<= 1) {
            int v = (t >= d) ? sm[t - d] : 0;
            __syncthreads();
            sm[t] += v;
            __syncthreads();
        }
        int excl = sm[t] - s3 + carryS;
        if (idx < N)     { offs[idx]     = excl;      cursor[idx]     = excl; }
        if (idx + 1 < N) { offs[idx + 1] = excl + x0; cursor[idx + 1] = excl + x0; }
        if (idx + 2 < N) { offs[idx + 2] = excl + s1; cursor[idx + 2] = excl + s1; }
        if (idx + 3 < N) { offs[idx + 3] = excl + s2; cursor[idx + 3] = excl + s2; }
        int chunkTotal = sm[1023];
        __syncthreads();
        if (t == 0) carryS += chunkTotal;
        __syncthreads();
    }
    if (t == 0) offs[N] = carryS;
}

__global__ void scatter_kernel(const int* __restrict__ recv, int* __restrict__ cursor,
                               int* __restrict__ perm, int E) {
    int i = blockIdx.x * blockDim.x + threadIdx.x;
    if (i < E) {
        int p = atomicAdd(&cursor[recv[i]], 1);
        perm[p] = i;
    }
}

// ---------------- received[n,:] = sum of incident edge rows (CSR gather, no atomics) ----
__global__ __launch_bounds__(256) void gather_kernel(
    const float* __restrict__ edges, const int* __restrict__ offs,
    const int* __restrict__ perm, float* __restrict__ received, int N)
{
    int w = threadIdx.x >> 6;
    int lane = threadIdx.x & 63;
    int n = blockIdx.x * 4 + w;
    if (n >= N) return;
    int s = offs[n], e = offs[n + 1];
    float acc = 0.f;
    for (int i = s; i < e; ++i) {
        int ed = perm[i];
        acc += edges[(size_t)ed * DD + lane];
    }
    received[(size_t)n * DD + lane] = acc;
}

// ---------------- prep: fold g @ W1[g-rows] into effective layer-1 biases ----------------
__global__ void prep_bias_kernel(const float* __restrict__ g,
                                 const float* __restrict__ We1, const float* __restrict__ be1,
                                 const float* __restrict__ Wn1, const float* __restrict__ bn1,
                                 float* __restrict__ be1e, float* __restrict__ bn1e) {
    int j = threadIdx.x;  // 64 threads
    float a = be1[j];
    float b = bn1[j];
    for (int k = 0; k < DD; ++k) {
        float gk = g[k];
        a = fmaf(gk, We1[(192 + k) * DD + j], a);
        b = fmaf(gk, Wn1[(128 + k) * DD + j], b);
    }
    be1e[j] = a;
    bn1e[j] = b;
}

// ---------------- edge update: 64 edges x 64 outputs per 256-thread block ----------------
__global__ __launch_bounds__(256) void edge_kernel(
    const float* __restrict__ edges_in, const float* __restrict__ nodes_in,
    const int* __restrict__ senders, const int* __restrict__ receivers,
    const float* __restrict__ W1, const float* __restrict__ b1e,
    const float* __restrict__ W2, const float* __restrict__ b2,
    float* __restrict__ edges_out, float* __restrict__ agg_e, int E)
{
    __shared__ __align__(16) float AT[64 * 68];  // x^T chunk: AT[k][e], reused for h^T
    __shared__ float PS[16 * 65];
    __shared__ int sidx[64];
    __shared__ int ridx[64];

    const int t  = threadIdx.x;
    const int eq = t >> 4, oq = t & 15;
    const int e0 = eq << 2, j0 = oq << 2;
    const int le = t >> 2, lq = t & 3;
    const int eb = blockIdx.x << 6;
    const int evalid = min(64, E - eb);

    if (t < 64) sidx[t] = (t < evalid) ? senders[eb + t] : 0;
    else if (t < 128) ridx[t - 64] = (t - 64 < evalid) ? receivers[eb + t - 64] : 0;

    float4 bv = *(const float4*)(b1e + j0);
    float acc[4][4];
#pragma unroll
    for (int a = 0; a < 4; ++a) { acc[a][0] = bv.x; acc[a][1] = bv.y; acc[a][2] = bv.z; acc[a][3] = bv.w; }

    for (int c = 0; c < 3; ++c) {
        __syncthreads();
        if (le < evalid) {
            const float* src;
            if (c == 0)      src = edges_in + (size_t)(eb + le) * DD;
            else if (c == 1) src = nodes_in + (size_t)sidx[le] * DD;
            else             src = nodes_in + (size_t)ridx[le] * DD;
#pragma unroll
            for (int i = 0; i < 4; ++i) {
                float4 v = *(const float4*)(src + lq * 16 + i * 4);
                int k = lq * 16 + i * 4;
                AT[(k + 0) * 68 + le] = v.x;
                AT[(k + 1) * 68 + le] = v.y;
                AT[(k + 2) * 68 + le] = v.z;
                AT[(k + 3) * 68 + le] = v.w;
            }
        } else {
#pragma unroll
            for (int i = 0; i < 16; ++i) AT[(lq * 16 + i) * 68 + le] = 0.f;
        }
        __syncthreads();
        const float* wb = W1 + c * (DD * DD);
#pragma unroll 4
        for (int kk = 0; kk < DD; ++kk) {
            float4 av = *(const float4*)&AT[kk * 68 + e0];
            float4 wv = *(const float4*)(wb + kk * DD + j0);
            float A4[4] = {av.x, av.y, av.z, av.w};
            float W4[4] = {wv.x, wv.y, wv.z, wv.w};
#pragma unroll
            for (int a = 0; a < 4; ++a)
#pragma unroll
                for (int b = 0; b < 4; ++b)
                    acc[a][b] = fmaf(A4[a], W4[b], acc[a][b]);
        }
    }

    __syncthreads();
#pragma unroll
    for (int b = 0; b < 4; ++b)
#pragma unroll
        for (int a = 0; a < 4; ++a)
            AT[(j0 + b) * 68 + (e0 + a)] = fmaxf(acc[a][b], 0.f);
    __syncthreads();

    float4 b2v = *(const float4*)(b2 + j0);
    float acc2[4][4];
#pragma unroll
    for (int a = 0; a < 4; ++a) { acc2[a][0] = b2v.x; acc2[a][1] = b2v.y; acc2[a][2] = b2v.z; acc2[a][3] = b2v.w; }
#pragma unroll 4
    for (int kk = 0; kk < DD; ++kk) {
        float4 av = *(const float4*)&AT[kk * 68 + e0];
        float4 wv = *(const float4*)(W2 + kk * DD + j0);
        float A4[4] = {av.x, av.y, av.z, av.w};
        float W4[4] = {wv.x, wv.y, wv.z, wv.w};
#pragma unroll
        for (int a = 0; a < 4; ++a)
#pragma unroll
            for (int b = 0; b < 4; ++b)
                acc2[a][b] = fmaf(A4[a], W4[b], acc2[a][b]);
    }

#pragma unroll
    for (int a = 0; a < 4; ++a) {
        if (e0 + a < evalid) {
            float4 o; o.x = acc2[a][0]; o.y = acc2[a][1]; o.z = acc2[a][2]; o.w = acc2[a][3];
            *(float4*)(edges_out + (size_t)(eb + e0 + a) * DD + j0) = o;
        }
    }
#pragma unroll
    for (int b = 0; b < 4; ++b) {
        float s = 0.f;
#pragma unroll
        for (int a = 0; a < 4; ++a)
            if (e0 + a < evalid) s += acc2[a][b];
        PS[eq * 65 + j0 + b] = s;
    }
    __syncthreads();
    if (t < 64) {
        float s = 0.f;
#pragma unroll
        for (int q = 0; q < 16; ++q) s += PS[q * 65 + t];
        atomicAdd(agg_e + t, s);
    }
}

// ---------------- node update: 64 nodes x 64 outputs per 256-thread block ----------------
__global__ __launch_bounds__(256) void node_kernel(
    const float* __restrict__ nodes_in, const float* __restrict__ received,
    const float* __restrict__ W1, const float* __restrict__ b1e,
    const float* __restrict__ W2, const float* __restrict__ b2,
    float* __restrict__ nodes_out, float* __restrict__ agg_n, int N)
{
    __shared__ __align__(16) float AT[64 * 68];
    __shared__ float PS[16 * 65];

    const int t  = threadIdx.x;
    const int eq = t >> 4, oq = t & 15;
    const int e0 = eq << 2, j0 = oq << 2;
    const int le = t >> 2, lq = t & 3;
    const int nb = blockIdx.x << 6;
    const int nvalid = min(64, N - nb);

    float4 bv = *(const float4*)(b1e + j0);
    float acc[4][4];
#pragma unroll
    for (int a = 0; a < 4; ++a) { acc[a][0] = bv.x; acc[a][1] = bv.y; acc[a][2] = bv.z; acc[a][3] = bv.w; }

    for (int c = 0; c < 2; ++c) {
        __syncthreads();
        if (le < nvalid) {
            const float* src = (c == 0 ? nodes_in : received) + (size_t)(nb + le) * DD;
#pragma unroll
            for (int i = 0; i < 4; ++i) {
                float4 v = *(const float4*)(src + lq * 16 + i * 4);
                int k = lq * 16 + i * 4;
                AT[(k + 0) * 68 + le] = v.x;
                AT[(k + 1) * 68 + le] = v.y;
                AT[(k + 2) * 68 + le] = v.z;
                AT[(k + 3) * 68 + le] = v.w;
            }
        } else {
#pragma unroll
            for (int i = 0; i < 16; ++i) AT[(lq * 16 + i) * 68 + le] = 0.f;
        }
        __syncthreads();
        const float* wb = W1 + c * (DD * DD);
#pragma unroll 4
        for (int kk = 0; kk < DD; ++kk) {
            float4 av = *(const float4*)&AT[kk * 68 + e0];
            float4 wv = *(const float4*)(wb + kk * DD + j0);
            float A4[4] = {av.x, av.y, av.z, av.w};
            float W4[4] = {wv.x, wv.y, wv.z, wv.w};
#pragma unroll
            for (int a = 0; a < 4; ++a)
#pragma unroll
                for (int b = 0; b < 4; ++b)
                    acc[a][b] = fmaf(A4[a], W4[b], acc[a][b]);
        }
    }

    __syncthreads();
#pragma unroll
    for (int b = 0; b < 4; ++b)
#pragma unroll
        for (int a = 0; a < 4; ++a)
            AT[(j0 + b) * 68 + (e0 + a)] = fmaxf(acc[a][b], 0.f);
    __syncthreads();

    float4 b2v = *(const float4*)(b2 + j0);
    float acc2[4][4];
#pragma unroll
    for (int a = 0; a < 4; ++a) { acc2[a][0] = b2v.x; acc2[a][1] = b2v.y; acc2[a][2] = b2v.z; acc2[a][3] = b2v.w; }
#pragma unroll 4
    for (int kk = 0; kk < DD; ++kk) {
        float4 av = *(const float4*)&AT[kk * 68 + e0];
        float4 wv = *(const float4*)(W2 + kk * DD + j0);
        float A4[4] = {av.x, av.y, av.z, av.w};
        float W4[4] = {wv.x, wv.y, wv.z, wv.w};
#pragma unroll
        for (int a = 0; a < 4; ++a)
#pragma unroll
            for (int b = 0; b < 4; ++b)
                acc2[a][b] = fmaf(A4[a], W4[b], acc2[a][b]);
    }

#pragma unroll
    for (int a = 0; a < 4; ++a) {
        if (e0 + a < nvalid) {
            float4 o; o.x = acc2[a][0]; o.y = acc2[a][1]; o.z = acc2[a][2]; o.w = acc2[a][3];
            *(float4*)(nodes_out + (size_t)(nb + e0 + a) * DD + j0) = o;
        }
    }
#pragma unroll
    for (int b = 0; b < 4; ++b) {
        float s = 0.f;
#pragma unroll
        for (int a = 0; a < 4; ++a)
            if (e0 + a < nvalid) s += acc2[a][b];
        PS[eq * 65 + j0 + b] = s;
    }
    __syncthreads();
    if (t < 64) {
        float s = 0.f;
#pragma unroll
        for (int q = 0; q < 16; ++q) s += PS[q * 65 + t];
        atomicAdd(agg_n + t, s);
    }
}

// ---------------- global update (tiny) ----------------
__global__ void global_kernel(const float* __restrict__ agg_n, const float* __restrict__ agg_e,
                              const float* __restrict__ g_in,
                              const float* __restrict__ Wg1, const float* __restrict__ bg1,
                              const float* __restrict__ Wg2, const float* __restrict__ bg2,
                              float* __restrict__ g_out)
{
    __shared__ float h[64];
    int j = threadIdx.x;  // 64 threads
    float a = bg1[j];
    for (int k = 0; k < DD; ++k) a = fmaf(agg_n[k], Wg1[k * DD + j], a);
    for (int k = 0; k < DD; ++k) a = fmaf(agg_e[k], Wg1[(64 + k) * DD + j], a);
    for (int k = 0; k < DD; ++k) a = fmaf(g_in[k],  Wg1[(128 + k) * DD + j], a);
    h[j] = fmaxf(a, 0.f);
    __syncthreads();
    float o = bg2[j];
    for (int k = 0; k < DD; ++k) o = fmaf(h[k], Wg2[k * DD + j], o);
    g_out[j] = o;
}

extern "C" void kernel_launch(void* const* d_in, const int* in_sizes, int n_in,
                              void* d_out, int out_size, void* d_ws, size_t ws_size,
                              hipStream_t stream) {
    const float* nodes0 = (const float*)d_in[0];
    const float* edges0 = (const float*)d_in[1];
    const float* g0     = (const float*)d_in[2];
    const int* senders   = (const int*)d_in[3];
    const int* receivers = (const int*)d_in[4];
    const float* We1 = (const float*)d_in[5];
    const float* be1 = (const float*)d_in[6];
    const float* We2 = (const float*)d_in[7];
    const float* be2 = (const float*)d_in[8];
    const float* Wn1 = (const float*)d_in[9];
    const float* bn1 = (const float*)d_in[10];
    const float* Wn2 = (const float*)d_in[11];
    const float* bn2 = (const float*)d_in[12];
    const float* Wg1 = (const float*)d_in[13];
    const float* bg1 = (const float*)d_in[14];
    const float* Wg2 = (const float*)d_in[15];
    const float* bg2 = (const float*)d_in[16];

    const int N = in_sizes[0] / DD;
    const int E = in_sizes[1] / DD;

    float* out_nodes = (float*)d_out;
    float* out_edges = out_nodes + (size_t)N * DD;
    float* out_g     = out_edges + (size_t)E * DD;

    float* ws = (float*)d_ws;
    float* received = ws;                              // N*64 floats
    float* aggs = received + (size_t)N * DD;           // 512 floats
    float* agg_n = aggs;          // 64
    float* agg_e = aggs + 64;     // 64
    float* b1e   = aggs + 128;    // 64
    float* b1n   = aggs + 192;    // 64
    float* g1    = aggs + 256;    // 64
    float* g2    = aggs + 320;    // 64
    int* counts = (int*)(aggs + 512);                  // N
    int* offs   = counts + N;                          // N+1
    int* cursor = offs + N + 1;                        // N
    int* perm   = cursor + N;                          // E

    const int eblocks = (E + 63) / 64;
    const int nblocks = (N + 63) / 64;

    // ---- CSR build (once; receivers identical across steps) ----
    zero_counts_kernel<<<(N + 255) / 256, 256, 0, stream>>>(counts, N);
    hist_kernel<<<(E + 255) / 256, 256, 0, stream>>>(receivers, counts, E);
    scan_kernel<<<1, 1024, 0, stream>>>(counts, offs, cursor, N);
    scatter_kernel<<<(E + 255) / 256, 256, 0, stream>>>(receivers, cursor, perm, E);

    for (int s = 0; s < 3; ++s) {
        const float* nsrc = (s == 0) ? nodes0 : out_nodes;
        const float* esrc = (s == 0) ? edges0 : out_edges;
        const float* gin  = (s == 0) ? g0 : ((s == 1) ? g1 : g2);
        float* gout       = (s == 2) ? out_g : ((s == 0) ? g1 : g2);

        hipMemsetAsync(aggs, 0, 128 * sizeof(float), stream);
        prep_bias_kernel<<<1, 64, 0, stream>>>(gin, We1, be1, Wn1, bn1, b1e, b1n);
        edge_kernel<<<eblocks, 256, 0, stream>>>(esrc, nsrc, senders, receivers,
                                                 We1, b1e, We2, be2,
                                                 out_edges, agg_e, E);
        gather_kernel<<<(N + 3) / 4, 256, 0, stream>>>(out_edges, offs, perm, received, N);
        node_kernel<<<nblocks, 256, 0, stream>>>(nsrc, received, Wn1, b1n, Wn2, bn2,
                                                 out_nodes, agg_n, N);
        global_kernel<<<1, 64, 0, stream>>>(agg_n, agg_e, gin, Wg1, bg1, Wg2, bg2, gout);
    }
}

// Round 3
// 3355.996 us; speedup vs baseline: 1.8900x; 1.1496x over previous
//
#include <hip/hip_runtime.h>

#define DD 64
typedef unsigned int uint32;
typedef unsigned short ushort16;
typedef short bf16x8 __attribute__((ext_vector_type(8)));
typedef float f32x4 __attribute__((ext_vector_type(4)));

__device__ __forceinline__ ushort16 f2bf(float x) {
    uint32 u = __float_as_uint(x);
    uint32 r = (u + 0x7FFFu + ((u >> 16) & 1u)) >> 16;
    return (ushort16)r;
}
__device__ __forceinline__ float bf2f(ushort16 h) {
    return __uint_as_float(((uint32)h) << 16);
}

// ---------------- CSR build (receivers constant across steps; built once) ----------------
__global__ void zero_counts_kernel(int* __restrict__ counts, int N) {
    int i = blockIdx.x * blockDim.x + threadIdx.x;
    if (i < N) counts[i] = 0;
}

__global__ void hist_kernel(const int* __restrict__ recv, int* __restrict__ counts, int E) {
    int i = blockIdx.x * blockDim.x + threadIdx.x;
    if (i < E) atomicAdd(&counts[recv[i]], 1);
}

__global__ __launch_bounds__(1024) void scan_kernel(const int* __restrict__ counts,
                                                    int* __restrict__ offs,
                                                    int* __restrict__ cursor, int N) {
    __shared__ int sm[1024];
    __shared__ int carryS;
    int t = threadIdx.x;
    if (t == 0) carryS = 0;
    __syncthreads();
    for (int base = 0; base < N; base += 4096) {
        int idx = base + t * 4;
        int x0 = (idx + 0 < N) ? counts[idx + 0] : 0;
        int x1 = (idx + 1 < N) ? counts[idx + 1] : 0;
        int x2 = (idx + 2 < N) ? counts[idx + 2] : 0;
        int x3 = (idx + 3 < N) ? counts[idx + 3] : 0;
        int s1 = x0 + x1, s2 = s1 + x2, s3 = s2 + x3;
        sm[t] = s3;
        __syncthreads();
        for (int d = 1; d < 1024; d <<= 1) {
            int v = (t >= d) ? sm[t - d] : 0;
            __syncthreads();
            sm[t] += v;
            __syncthreads();
        }
        int excl = sm[t] - s3 + carryS;
        if (idx < N)     { offs[idx]     = excl;      cursor[idx]     = excl; }
        if (idx + 1 < N) { offs[idx + 1] = excl + x0; cursor[idx + 1] = excl + x0; }
        if (idx + 2 < N) { offs[idx + 2] = excl + s1; cursor[idx + 2] = excl + s1; }
        if (idx + 3 < N) { offs[idx + 3] = excl + s2; cursor[idx + 3] = excl + s2; }
        int chunkTotal = sm[1023];
        __syncthreads();
        if (t == 0) carryS += chunkTotal;
        __syncthreads();
    }
    if (t == 0) offs[N] = carryS;
}

__global__ void scatter_kernel(const int* __restrict__ recv, int* __restrict__ cursor,
                               int* __restrict__ perm, int E) {
    int i = blockIdx.x * blockDim.x + threadIdx.x;
    if (i < E) {
        int p = atomicAdd(&cursor[recv[i]], 1);
        perm[p] = i;
    }
}

// ---------------- received[n,:] = sum of incident edge rows ----------------
__global__ __launch_bounds__(256) void gather_kernel(
    const float* __restrict__ edges, const int* __restrict__ offs,
    const int* __restrict__ perm, float* __restrict__ received, int N)
{
    int w = threadIdx.x >> 6;
    int lane = threadIdx.x & 63;
    int n = blockIdx.x * 4 + w;
    if (n >= N) return;
    int s = offs[n], e = offs[n + 1];
    float acc = 0.f;
    for (int i = s; i < e; ++i) {
        int ed = perm[i];
        acc += edges[(size_t)ed * DD + lane];
    }
    received[(size_t)n * DD + lane] = acc;
}

// ---------------- prep: fold g @ W1[g-rows] into effective layer-1 biases --------------
__global__ void prep_bias_kernel(const float* __restrict__ g,
                                 const float* __restrict__ We1, const float* __restrict__ be1,
                                 const float* __restrict__ Wn1, const float* __restrict__ bn1,
                                 float* __restrict__ be1e, float* __restrict__ bn1e) {
    int j = threadIdx.x;  // 64 threads
    float a = be1[j];
    float b = bn1[j];
    for (int k = 0; k < DD; ++k) {
        float gk = g[k];
        a = fmaf(gk, We1[(192 + k) * DD + j], a);
        b = fmaf(gk, Wn1[(128 + k) * DD + j], b);
    }
    be1e[j] = a;
    bn1e[j] = b;
}

// ---------------- prep: split nodes fp32 -> packed (hi<<16)|lo bf16 pair ---------------
__global__ void prep_nodes_kernel(const float* __restrict__ src, uint32* __restrict__ dst,
                                  int total) {
    int i = blockIdx.x * blockDim.x + threadIdx.x;
    if (i < total) {
        float x = src[i];
        ushort16 hi = f2bf(x);
        ushort16 lo = f2bf(x - bf2f(hi));
        dst[i] = ((uint32)hi << 16) | (uint32)lo;
    }
}

// ---------------- prep: weights -> hi/lo bf16, pre-swizzled into B-fragment order ------
// w1: [ks=6][t=4][ver=2][lane=64][i=8], source rows 0..191 of We1 (g rows folded to bias)
// w2: [ks=2][t=4][ver=2][lane=64][i=8]
__global__ void prep_weights_kernel(const float* __restrict__ We1, const float* __restrict__ We2,
                                    unsigned short* __restrict__ w1, unsigned short* __restrict__ w2) {
    int tid = blockIdx.x * blockDim.x + threadIdx.x;
    if (tid < 12288) {
        int i = tid & 7, lane = (tid >> 3) & 63, tt = (tid >> 9) & 3, ks = tid >> 11;
        int k = ks * 32 + (lane >> 4) * 8 + i;
        int n = tt * 16 + (lane & 15);
        float x = We1[k * DD + n];
        ushort16 hi = f2bf(x);
        ushort16 lo = f2bf(x - bf2f(hi));
        w1[(((ks * 4 + tt) * 2 + 0) * 64 + lane) * 8 + i] = hi;
        w1[(((ks * 4 + tt) * 2 + 1) * 64 + lane) * 8 + i] = lo;
    }
    if (tid < 4096) {
        int i = tid & 7, lane = (tid >> 3) & 63, tt = (tid >> 9) & 3, ks = tid >> 11;
        int k = ks * 32 + (lane >> 4) * 8 + i;
        int n = tt * 16 + (lane & 15);
        float x = We2[k * DD + n];
        ushort16 hi = f2bf(x);
        ushort16 lo = f2bf(x - bf2f(hi));
        w2[(((ks * 4 + tt) * 2 + 0) * 64 + lane) * 8 + i] = hi;
        w2[(((ks * 4 + tt) * 2 + 1) * 64 + lane) * 8 + i] = lo;
    }
}

// ---------------- edge update: MFMA split-bf16, 64 edges/block, 4 waves ----------------
__global__ __launch_bounds__(256) void edge_kernel_mfma(
    const float* __restrict__ edges_in, const uint32* __restrict__ nodes_pk,
    const int* __restrict__ senders, const int* __restrict__ receivers,
    const unsigned short* __restrict__ w1, const float* __restrict__ b1,
    const unsigned short* __restrict__ w2, const float* __restrict__ b2,
    float* __restrict__ edges_out, float* __restrict__ agg_e, int E)
{
    __shared__ int sidx[64];
    __shared__ int ridx[64];
    __shared__ float PS[4][64];
    __shared__ __align__(16) unsigned short hbuf[2][4][16][64];  // 16 KB, reused as C fp32

    const int t = threadIdx.x;
    const int w = t >> 6, l = t & 63;
    const int eb = blockIdx.x << 6;

    if (t < 64) sidx[t] = (eb + t < E) ? senders[eb + t] : 0;
    else if (t < 128) ridx[t - 64] = (eb + t - 64 < E) ? receivers[eb + t - 64] : 0;
    __syncthreads();

    const int lm = l & 15;            // row within wave tile / col within n-tile
    const int kq = l >> 4;            // k-quarter
    const int mrow = (w << 4) + lm;   // block-local edge row for A-frags
    const int grow = eb + mrow;

    f32x4 acc[4];
#pragma unroll
    for (int tt = 0; tt < 4; ++tt) {
        float b = b1[tt * 16 + lm];
        acc[tt][0] = b; acc[tt][1] = b; acc[tt][2] = b; acc[tt][3] = b;
    }

    const float*  erow = edges_in + (size_t)min(grow, E - 1) * DD;
    const uint32* srow = nodes_pk + (size_t)sidx[mrow] * DD;
    const uint32* rrow = nodes_pk + (size_t)ridx[mrow] * DD;

    // GEMM1: K=192, 6 k-steps of 32 (chunks: edges / sender / receiver)
#pragma unroll
    for (int ks = 0; ks < 6; ++ks) {
        bf16x8 ah, al;
        const int k0 = (ks & 1) * 32 + kq * 8;
        if (ks < 2) {
            float4 x0 = *(const float4*)(erow + k0);
            float4 x1 = *(const float4*)(erow + k0 + 4);
            float xs[8] = {x0.x, x0.y, x0.z, x0.w, x1.x, x1.y, x1.z, x1.w};
#pragma unroll
            for (int i = 0; i < 8; ++i) {
                ushort16 hi = f2bf(xs[i]);
                ah[i] = (short)hi;
                al[i] = (short)f2bf(xs[i] - bf2f(hi));
            }
        } else {
            const uint32* nr = (ks < 4) ? srow : rrow;
            uint4 u0 = *(const uint4*)(nr + k0);
            uint4 u1 = *(const uint4*)(nr + k0 + 4);
            uint32 us[8] = {u0.x, u0.y, u0.z, u0.w, u1.x, u1.y, u1.z, u1.w};
#pragma unroll
            for (int i = 0; i < 8; ++i) {
                ah[i] = (short)(us[i] >> 16);
                al[i] = (short)(us[i] & 0xFFFFu);
            }
        }
#pragma unroll
        for (int tt = 0; tt < 4; ++tt) {
            bf16x8 bh = *(const bf16x8*)(w1 + (size_t)(((ks * 4 + tt) * 2 + 0) * 64 + l) * 8);
            bf16x8 bl = *(const bf16x8*)(w1 + (size_t)(((ks * 4 + tt) * 2 + 1) * 64 + l) * 8);
            acc[tt] = __builtin_amdgcn_mfma_f32_16x16x32_bf16(ah, bh, acc[tt], 0, 0, 0);
            acc[tt] = __builtin_amdgcn_mfma_f32_16x16x32_bf16(ah, bl, acc[tt], 0, 0, 0);
            acc[tt] = __builtin_amdgcn_mfma_f32_16x16x32_bf16(al, bh, acc[tt], 0, 0, 0);
        }
    }

    // ReLU -> h in LDS as hi/lo, XOR-swizzled (rows are 128B: T2 case)
    char* hh = (char*)&hbuf[0][w][0][0];
    char* hl = (char*)&hbuf[1][w][0][0];
#pragma unroll
    for (int tt = 0; tt < 4; ++tt) {
#pragma unroll
        for (int r = 0; r < 4; ++r) {
            int row = (kq << 2) + r;         // C/D row = (lane>>4)*4 + reg
            int col = (tt << 4) + lm;
            float hv = fmaxf(acc[tt][r], 0.f);
            ushort16 hi = f2bf(hv);
            ushort16 lo = f2bf(hv - bf2f(hi));
            int slot = col >> 3;
            int boff = (row << 7) + (((slot ^ (row & 7)) & 7) << 4) + ((col & 7) << 1);
            *(unsigned short*)(hh + boff) = hi;
            *(unsigned short*)(hl + boff) = lo;
        }
    }
    __syncthreads();

    // GEMM2: K=64, 2 k-steps
    f32x4 acc2[4];
#pragma unroll
    for (int tt = 0; tt < 4; ++tt) {
        float b = b2[tt * 16 + lm];
        acc2[tt][0] = b; acc2[tt][1] = b; acc2[tt][2] = b; acc2[tt][3] = b;
    }
#pragma unroll
    for (int ks = 0; ks < 2; ++ks) {
        int row = lm;
        int slotb = kq + (ks << 2);
        int boff = (row << 7) + (((slotb ^ (row & 7)) & 7) << 4);
        bf16x8 ah = *(const bf16x8*)(hh + boff);
        bf16x8 al = *(const bf16x8*)(hl + boff);
#pragma unroll
        for (int tt = 0; tt < 4; ++tt) {
            bf16x8 bh = *(const bf16x8*)(w2 + (size_t)(((ks * 4 + tt) * 2 + 0) * 64 + l) * 8);
            bf16x8 bl = *(const bf16x8*)(w2 + (size_t)(((ks * 4 + tt) * 2 + 1) * 64 + l) * 8);
            acc2[tt] = __builtin_amdgcn_mfma_f32_16x16x32_bf16(ah, bh, acc2[tt], 0, 0, 0);
            acc2[tt] = __builtin_amdgcn_mfma_f32_16x16x32_bf16(ah, bl, acc2[tt], 0, 0, 0);
            acc2[tt] = __builtin_amdgcn_mfma_f32_16x16x32_bf16(al, bh, acc2[tt], 0, 0, 0);
        }
    }

    // agg_e partial: per-col sums (cols this lane owns), reduce 4 lanes sharing a col
#pragma unroll
    for (int tt = 0; tt < 4; ++tt) {
        float s = acc2[tt][0] + acc2[tt][1] + acc2[tt][2] + acc2[tt][3];
        s += __shfl_xor(s, 16, 64);
        s += __shfl_xor(s, 32, 64);
        if (l < 16) PS[w][tt * 16 + l] = s;
    }

    __syncthreads();  // hbuf (incl. other waves' h) now dead; PS complete

    // C writeback: transpose through swizzled LDS fp32, then coalesced float4 row stores
    float* cw = (float*)hbuf + (w << 10);  // wave's 16x64 fp32 region (4 KB)
#pragma unroll
    for (int tt = 0; tt < 4; ++tt) {
#pragma unroll
        for (int r = 0; r < 4; ++r) {
            int row = (kq << 2) + r;
            int col = (tt << 4) + lm;
            int slot = col >> 2;
            int boff = (row << 8) + (((slot ^ (row & 15)) & 15) << 4) + ((col & 3) << 2);
            *(float*)((char*)cw + boff) = acc2[tt][r];
        }
    }
    __syncthreads();
    {
        int rr = lm;
        int gr = eb + (w << 4) + rr;
        float4* dst = (float4*)(edges_out + (size_t)gr * DD);
#pragma unroll
        for (int j = 0; j < 4; ++j) {
            int fc = kq + (j << 2);
            int boff = (rr << 8) + (((fc ^ (rr & 15)) & 15) << 4);
            float4 v = *(float4*)((char*)cw + boff);
            if (gr < E) dst[fc] = v;
        }
    }
    if (t < 64) {
        float s = PS[0][t] + PS[1][t] + PS[2][t] + PS[3][t];
        atomicAdd(agg_e + t, s);
    }
}

// ---------------- node update: fp32 VALU (unchanged; ~5% of time) ----------------------
__global__ __launch_bounds__(256) void node_kernel(
    const float* __restrict__ nodes_in, const float* __restrict__ received,
    const float* __restrict__ W1, const float* __restrict__ b1e,
    const float* __restrict__ W2, const float* __restrict__ b2,
    float* __restrict__ nodes_out, float* __restrict__ agg_n, int N)
{
    __shared__ __align__(16) float AT[64 * 68];
    __shared__ float PS[16 * 65];

    const int t  = threadIdx.x;
    const int eq = t >> 4, oq = t & 15;
    const int e0 = eq << 2, j0 = oq << 2;
    const int le = t >> 2, lq = t & 3;
    const int nb = blockIdx.x << 6;
    const int nvalid = min(64, N - nb);

    float4 bv = *(const float4*)(b1e + j0);
    float acc[4][4];
#pragma unroll
    for (int a = 0; a < 4; ++a) { acc[a][0] = bv.x; acc[a][1] = bv.y; acc[a][2] = bv.z; acc[a][3] = bv.w; }

    for (int c = 0; c < 2; ++c) {
        __syncthreads();
        if (le < nvalid) {
            const float* src = (c == 0 ? nodes_in : received) + (size_t)(nb + le) * DD;
#pragma unroll
            for (int i = 0; i < 4; ++i) {
                float4 v = *(const float4*)(src + lq * 16 + i * 4);
                int k = lq * 16 + i * 4;
                AT[(k + 0) * 68 + le] = v.x;
                AT[(k + 1) * 68 + le] = v.y;
                AT[(k + 2) * 68 + le] = v.z;
                AT[(k + 3) * 68 + le] = v.w;
            }
        } else {
#pragma unroll
            for (int i = 0; i < 16; ++i) AT[(lq * 16 + i) * 68 + le] = 0.f;
        }
        __syncthreads();
        const float* wb = W1 + c * (DD * DD);
#pragma unroll 4
        for (int kk = 0; kk < DD; ++kk) {
            float4 av = *(const float4*)&AT[kk * 68 + e0];
            float4 wv = *(const float4*)(wb + kk * DD + j0);
            float A4[4] = {av.x, av.y, av.z, av.w};
            float W4[4] = {wv.x, wv.y, wv.z, wv.w};
#pragma unroll
            for (int a = 0; a < 4; ++a)
#pragma unroll
                for (int b = 0; b < 4; ++b)
                    acc[a][b] = fmaf(A4[a], W4[b], acc[a][b]);
        }
    }

    __syncthreads();
#pragma unroll
    for (int b = 0; b < 4; ++b)
#pragma unroll
        for (int a = 0; a < 4; ++a)
            AT[(j0 + b) * 68 + (e0 + a)] = fmaxf(acc[a][b], 0.f);
    __syncthreads();

    float4 b2v = *(const float4*)(b2 + j0);
    float acc2[4][4];
#pragma unroll
    for (int a = 0; a < 4; ++a) { acc2[a][0] = b2v.x; acc2[a][1] = b2v.y; acc2[a][2] = b2v.z; acc2[a][3] = b2v.w; }
#pragma unroll 4
    for (int kk = 0; kk < DD; ++kk) {
        float4 av = *(const float4*)&AT[kk * 68 + e0];
        float4 wv = *(const float4*)(W2 + kk * DD + j0);
        float A4[4] = {av.x, av.y, av.z, av.w};
        float W4[4] = {wv.x, wv.y, wv.z, wv.w};
#pragma unroll
        for (int a = 0; a < 4; ++a)
#pragma unroll
            for (int b = 0; b < 4; ++b)
                acc2[a][b] = fmaf(A4[a], W4[b], acc2[a][b]);
    }

#pragma unroll
    for (int a = 0; a < 4; ++a) {
        if (e0 + a < nvalid) {
            float4 o; o.x = acc2[a][0]; o.y = acc2[a][1]; o.z = acc2[a][2]; o.w = acc2[a][3];
            *(float4*)(nodes_out + (size_t)(nb + e0 + a) * DD + j0) = o;
        }
    }
#pragma unroll
    for (int b = 0; b < 4; ++b) {
        float s = 0.f;
#pragma unroll
        for (int a = 0; a < 4; ++a)
            if (e0 + a < nvalid) s += acc2[a][b];
        PS[eq * 65 + j0 + b] = s;
    }
    __syncthreads();
    if (t < 64) {
        float s = 0.f;
#pragma unroll
        for (int q = 0; q < 16; ++q) s += PS[q * 65 + t];
        atomicAdd(agg_n + t, s);
    }
}

// ---------------- global update (tiny) ----------------
__global__ void global_kernel(const float* __restrict__ agg_n, const float* __restrict__ agg_e,
                              const float* __restrict__ g_in,
                              const float* __restrict__ Wg1, const float* __restrict__ bg1,
                              const float* __restrict__ Wg2, const float* __restrict__ bg2,
                              float* __restrict__ g_out)
{
    __shared__ float h[64];
    int j = threadIdx.x;  // 64 threads
    float a = bg1[j];
    for (int k = 0; k < DD; ++k) a = fmaf(agg_n[k], Wg1[k * DD + j], a);
    for (int k = 0; k < DD; ++k) a = fmaf(agg_e[k], Wg1[(64 + k) * DD + j], a);
    for (int k = 0; k < DD; ++k) a = fmaf(g_in[k],  Wg1[(128 + k) * DD + j], a);
    h[j] = fmaxf(a, 0.f);
    __syncthreads();
    float o = bg2[j];
    for (int k = 0; k < DD; ++k) o = fmaf(h[k], Wg2[k * DD + j], o);
    g_out[j] = o;
}

extern "C" void kernel_launch(void* const* d_in, const int* in_sizes, int n_in,
                              void* d_out, int out_size, void* d_ws, size_t ws_size,
                              hipStream_t stream) {
    const float* nodes0 = (const float*)d_in[0];
    const float* edges0 = (const float*)d_in[1];
    const float* g0     = (const float*)d_in[2];
    const int* senders   = (const int*)d_in[3];
    const int* receivers = (const int*)d_in[4];
    const float* We1 = (const float*)d_in[5];
    const float* be1 = (const float*)d_in[6];
    const float* We2 = (const float*)d_in[7];
    const float* be2 = (const float*)d_in[8];
    const float* Wn1 = (const float*)d_in[9];
    const float* bn1 = (const float*)d_in[10];
    const float* Wn2 = (const float*)d_in[11];
    const float* bn2 = (const float*)d_in[12];
    const float* Wg1 = (const float*)d_in[13];
    const float* bg1 = (const float*)d_in[14];
    const float* Wg2 = (const float*)d_in[15];
    const float* bg2 = (const float*)d_in[16];

    const int N = in_sizes[0] / DD;
    const int E = in_sizes[1] / DD;

    float* out_nodes = (float*)d_out;
    float* out_edges = out_nodes + (size_t)N * DD;
    float* out_g     = out_edges + (size_t)E * DD;

    float* ws = (float*)d_ws;
    float* received = ws;                              // N*64 floats
    float* aggs = received + (size_t)N * DD;           // 512 floats
    float* agg_n = aggs;          // 64
    float* agg_e = aggs + 64;     // 64
    float* b1e   = aggs + 128;    // 64
    float* b1n   = aggs + 192;    // 64
    float* g1    = aggs + 256;    // 64
    float* g2    = aggs + 320;    // 64
    int* counts = (int*)(aggs + 512);                  // N
    int* offs   = counts + N;                          // N+4 (padded for alignment)
    int* cursor = offs + N + 4;                        // N
    int* perm   = cursor + N;                          // E
    uint32* nodes_pk = (uint32*)(perm + E);            // N*64 (16B-aligned)
    unsigned short* w1 = (unsigned short*)(nodes_pk + (size_t)N * DD);  // 24576
    unsigned short* w2 = w1 + 24576;                                    // 8192

    const int eblocks = (E + 63) / 64;
    const int nblocks = (N + 63) / 64;

    // ---- one-time: CSR build + weight split/swizzle ----
    zero_counts_kernel<<<(N + 255) / 256, 256, 0, stream>>>(counts, N);
    hist_kernel<<<(E + 255) / 256, 256, 0, stream>>>(receivers, counts, E);
    scan_kernel<<<1, 1024, 0, stream>>>(counts, offs, cursor, N);
    scatter_kernel<<<(E + 255) / 256, 256, 0, stream>>>(receivers, cursor, perm, E);
    prep_weights_kernel<<<48, 256, 0, stream>>>(We1, We2, w1, w2);

    for (int s = 0; s < 3; ++s) {
        const float* nsrc = (s == 0) ? nodes0 : out_nodes;
        const float* esrc = (s == 0) ? edges0 : out_edges;
        const float* gin  = (s == 0) ? g0 : ((s == 1) ? g1 : g2);
        float* gout       = (s == 2) ? out_g : ((s == 0) ? g1 : g2);

        hipMemsetAsync(aggs, 0, 128 * sizeof(float), stream);
        prep_bias_kernel<<<1, 64, 0, stream>>>(gin, We1, be1, Wn1, bn1, b1e, b1n);
        prep_nodes_kernel<<<(N * DD + 255) / 256, 256, 0, stream>>>(nsrc, nodes_pk, N * DD);
        edge_kernel_mfma<<<eblocks, 256, 0, stream>>>(esrc, nodes_pk, senders, receivers,
                                                      w1, b1e, w2, be2,
                                                      out_edges, agg_e, E);
        gather_kernel<<<(N + 3) / 4, 256, 0, stream>>>(out_edges, offs, perm, received, N);
        node_kernel<<<nblocks, 256, 0, stream>>>(nsrc, received, Wn1, b1n, Wn2, bn2,
                                                 out_nodes, agg_n, N);
        global_kernel<<<1, 64, 0, stream>>>(agg_n, agg_e, gin, Wg1, bg1, Wg2, bg2, gout);
    }
}

// Round 4
// 2310.589 us; speedup vs baseline: 2.7451x; 1.4524x over previous
//
#include <hip/hip_runtime.h>

#define DD 64
typedef unsigned int uint32;
typedef unsigned short ushort16;
typedef short bf16x8 __attribute__((ext_vector_type(8)));
typedef float f32x4 __attribute__((ext_vector_type(4)));

__device__ __forceinline__ ushort16 f2bf(float x) {
    uint32 u = __float_as_uint(x);
    uint32 r = (u + 0x7FFFu + ((u >> 16) & 1u)) >> 16;
    return (ushort16)r;
}
__device__ __forceinline__ float bf2f(ushort16 h) {
    return __uint_as_float(((uint32)h) << 16);
}

__device__ __forceinline__ void split8f(const float4& a, const float4& b, bf16x8& ah, bf16x8& al) {
    float xs[8] = {a.x, a.y, a.z, a.w, b.x, b.y, b.z, b.w};
#pragma unroll
    for (int i = 0; i < 8; ++i) {
        ushort16 hi = f2bf(xs[i]);
        ah[i] = (short)hi;
        al[i] = (short)f2bf(xs[i] - bf2f(hi));
    }
}
__device__ __forceinline__ void unpack8(const uint4& a, const uint4& b, bf16x8& ah, bf16x8& al) {
    uint32 us[8] = {a.x, a.y, a.z, a.w, b.x, b.y, b.z, b.w};
#pragma unroll
    for (int i = 0; i < 8; ++i) {
        ah[i] = (short)(us[i] >> 16);
        al[i] = (short)(us[i] & 0xFFFFu);
    }
}

// 1 k-step (K=32) of split-bf16 MFMA over 4 m-tiles x 4 n-tiles
__device__ __forceinline__ void mfma_ks(const unsigned short* __restrict__ wks, int l,
                                        const bf16x8* ah, const bf16x8* al, f32x4 (*acc)[4]) {
#pragma unroll
    for (int tt = 0; tt < 4; ++tt) {
        bf16x8 bh = *(const bf16x8*)(wks + ((size_t)(tt * 2 + 0) * 64 + l) * 8);
        bf16x8 bl = *(const bf16x8*)(wks + ((size_t)(tt * 2 + 1) * 64 + l) * 8);
#pragma unroll
        for (int m = 0; m < 4; ++m) {
            acc[m][tt] = __builtin_amdgcn_mfma_f32_16x16x32_bf16(ah[m], bh, acc[m][tt], 0, 0, 0);
            acc[m][tt] = __builtin_amdgcn_mfma_f32_16x16x32_bf16(ah[m], bl, acc[m][tt], 0, 0, 0);
            acc[m][tt] = __builtin_amdgcn_mfma_f32_16x16x32_bf16(al[m], bh, acc[m][tt], 0, 0, 0);
        }
    }
}

// ---------------- CSR build ----------------
__global__ void zero_counts_kernel(int* __restrict__ counts, int N) {
    int i = blockIdx.x * blockDim.x + threadIdx.x;
    if (i < N) counts[i] = 0;
}

__global__ void hist_kernel(const int* __restrict__ recv, int* __restrict__ counts, int E) {
    int i = blockIdx.x * blockDim.x + threadIdx.x;
    if (i < E) atomicAdd(&counts[recv[i]], 1);
}

__global__ __launch_bounds__(1024) void scan_kernel(const int* __restrict__ counts,
                                                    int* __restrict__ offs,
                                                    int* __restrict__ cursor, int N) {
    __shared__ int sm[1024];
    __shared__ int carryS;
    int t = threadIdx.x;
    if (t == 0) carryS = 0;
    __syncthreads();
    for (int base = 0; base < N; base += 4096) {
        int idx = base + t * 4;
        int x0 = (idx + 0 < N) ? counts[idx + 0] : 0;
        int x1 = (idx + 1 < N) ? counts[idx + 1] : 0;
        int x2 = (idx + 2 < N) ? counts[idx + 2] : 0;
        int x3 = (idx + 3 < N) ? counts[idx + 3] : 0;
        int s1 = x0 + x1, s2 = s1 + x2, s3 = s2 + x3;
        sm[t] = s3;
        __syncthreads();
        for (int d = 1; d < 1024; d <<= 1) {
            int v = (t >= d) ? sm[t - d] : 0;
            __syncthreads();
            sm[t] += v;
            __syncthreads();
        }
        int excl = sm[t] - s3 + carryS;
        if (idx < N)     { offs[idx]     = excl;      cursor[idx]     = excl; }
        if (idx + 1 < N) { offs[idx + 1] = excl + x0; cursor[idx + 1] = excl + x0; }
        if (idx + 2 < N) { offs[idx + 2] = excl + s1; cursor[idx + 2] = excl + s1; }
        if (idx + 3 < N) { offs[idx + 3] = excl + s2; cursor[idx + 3] = excl + s2; }
        int chunkTotal = sm[1023];
        __syncthreads();
        if (t == 0) carryS += chunkTotal;
        __syncthreads();
    }
    if (t == 0) offs[N] = carryS;
}

__global__ void scatter_kernel(const int* __restrict__ recv, int* __restrict__ cursor,
                               int* __restrict__ perm, int E) {
    int i = blockIdx.x * blockDim.x + threadIdx.x;
    if (i < E) {
        int p = atomicAdd(&cursor[recv[i]], 1);
        perm[p] = i;
    }
}

// ---------------- received[n,:] = sum of incident edge rows ----------------
__global__ __launch_bounds__(256) void gather_kernel(
    const float* __restrict__ edges, const int* __restrict__ offs,
    const int* __restrict__ perm, float* __restrict__ received, int N)
{
    int w = threadIdx.x >> 6;
    int lane = threadIdx.x & 63;
    int n = blockIdx.x * 4 + w;
    if (n >= N) return;
    int s = offs[n], e = offs[n + 1];
    float acc = 0.f;
    for (int i = s; i < e; ++i) {
        int ed = perm[i];
        acc += edges[(size_t)ed * DD + lane];
    }
    received[(size_t)n * DD + lane] = acc;
}

// ---------------- prep: fold g @ W1[g-rows] into effective layer-1 biases --------------
__global__ void prep_bias_kernel(const float* __restrict__ g,
                                 const float* __restrict__ We1, const float* __restrict__ be1,
                                 const float* __restrict__ Wn1, const float* __restrict__ bn1,
                                 float* __restrict__ be1e, float* __restrict__ bn1e) {
    int j = threadIdx.x;  // 64 threads
    float a = be1[j];
    float b = bn1[j];
    for (int k = 0; k < DD; ++k) {
        float gk = g[k];
        a = fmaf(gk, We1[(192 + k) * DD + j], a);
        b = fmaf(gk, Wn1[(128 + k) * DD + j], b);
    }
    be1e[j] = a;
    bn1e[j] = b;
}

// ---------------- prep: split nodes fp32 -> packed (hi<<16)|lo bf16 pair ---------------
__global__ void prep_nodes_kernel(const float* __restrict__ src, uint32* __restrict__ dst,
                                  int total) {
    int i = blockIdx.x * blockDim.x + threadIdx.x;
    if (i < total) {
        float x = src[i];
        ushort16 hi = f2bf(x);
        ushort16 lo = f2bf(x - bf2f(hi));
        dst[i] = ((uint32)hi << 16) | (uint32)lo;
    }
}

// ---------------- prep: weights -> hi/lo bf16, pre-swizzled into B-fragment order ------
__device__ __forceinline__ void prep_pack(const float* __restrict__ W, int nks,
                                          unsigned short* __restrict__ dst, int tid) {
    if (tid < nks * 2048) {
        int i = tid & 7, lane = (tid >> 3) & 63, tt = (tid >> 9) & 3, ks = tid >> 11;
        int k = ks * 32 + (lane >> 4) * 8 + i;
        int n = tt * 16 + (lane & 15);
        float x = W[k * DD + n];
        ushort16 hi = f2bf(x);
        ushort16 lo = f2bf(x - bf2f(hi));
        dst[(((ks * 4 + tt) * 2 + 0) * 64 + lane) * 8 + i] = hi;
        dst[(((ks * 4 + tt) * 2 + 1) * 64 + lane) * 8 + i] = lo;
    }
}

__global__ void prep_weights_kernel(const float* __restrict__ We1, const float* __restrict__ We2,
                                    const float* __restrict__ Wn1, const float* __restrict__ Wn2,
                                    unsigned short* __restrict__ we1p, unsigned short* __restrict__ we2p,
                                    unsigned short* __restrict__ wn1p, unsigned short* __restrict__ wn2p) {
    int tid = blockIdx.x * blockDim.x + threadIdx.x;
    prep_pack(We1, 6, we1p, tid);
    prep_pack(We2, 2, we2p, tid);
    prep_pack(Wn1, 4, wn1p, tid);
    prep_pack(Wn2, 2, wn2p, tid);
}

// ======================= edge update: 256 edges/block, 64/wave =========================
__global__ __launch_bounds__(256, 2) void edge_kernel_mfma(
    const float* __restrict__ edges_in, const uint32* __restrict__ nodes_pk,
    const int* __restrict__ senders, const int* __restrict__ receivers,
    const unsigned short* __restrict__ w1, const float* __restrict__ b1,
    const unsigned short* __restrict__ w2, const float* __restrict__ b2,
    float* __restrict__ edges_out, float* __restrict__ agg_e, int E)
{
    __shared__ unsigned short HB[4][4][2][1024];  // [wave][m][plane] 64 KB; reused as C fp32
    __shared__ float PS[4][64];

    const int t = threadIdx.x;
    const int w = t >> 6, l = t & 63;
    const int lm = l & 15, kq = l >> 4;
    const int base = (blockIdx.x << 8) + (w << 6);

    // indices first (gate the gathers)
    int gie[4], gis[4], gir[4];
#pragma unroll
    for (int m = 0; m < 4; ++m) {
        int row = base + (m << 4) + lm;
        int gi = min(row, E - 1);
        gie[m] = gi;
        gis[m] = senders[gi];
        gir[m] = receivers[gi];
    }

    // ---- issue edges-chunk raws ----
    float4 re[4][4];
#pragma unroll
    for (int m = 0; m < 4; ++m) {
        const float* p = edges_in + (size_t)gie[m] * DD + kq * 8;
        re[m][0] = *(const float4*)(p);
        re[m][1] = *(const float4*)(p + 4);
        re[m][2] = *(const float4*)(p + 32);
        re[m][3] = *(const float4*)(p + 36);
    }
    // ---- issue sender-chunk raws ----
    uint4 rs[4][4];
#pragma unroll
    for (int m = 0; m < 4; ++m) {
        const uint32* p = nodes_pk + (size_t)gis[m] * DD + kq * 8;
        rs[m][0] = *(const uint4*)(p);
        rs[m][1] = *(const uint4*)(p + 4);
        rs[m][2] = *(const uint4*)(p + 32);
        rs[m][3] = *(const uint4*)(p + 36);
    }

    f32x4 acc[4][4];
#pragma unroll
    for (int tt = 0; tt < 4; ++tt) {
        float b = b1[tt * 16 + lm];
#pragma unroll
        for (int m = 0; m < 4; ++m) { acc[m][tt][0] = b; acc[m][tt][1] = b; acc[m][tt][2] = b; acc[m][tt][3] = b; }
    }

    // ---- process edges chunk (ks 0,1) ----
#pragma unroll
    for (int ks2 = 0; ks2 < 2; ++ks2) {
        bf16x8 ah[4], al[4];
#pragma unroll
        for (int m = 0; m < 4; ++m) split8f(re[m][ks2 * 2], re[m][ks2 * 2 + 1], ah[m], al[m]);
        mfma_ks(w1 + (size_t)ks2 * 4096, l, ah, al, acc);
    }

    // ---- issue receiver-chunk raws ----
    uint4 rr[4][4];
#pragma unroll
    for (int m = 0; m < 4; ++m) {
        const uint32* p = nodes_pk + (size_t)gir[m] * DD + kq * 8;
        rr[m][0] = *(const uint4*)(p);
        rr[m][1] = *(const uint4*)(p + 4);
        rr[m][2] = *(const uint4*)(p + 32);
        rr[m][3] = *(const uint4*)(p + 36);
    }

    // ---- process sender chunk (ks 2,3) ----
#pragma unroll
    for (int ks2 = 0; ks2 < 2; ++ks2) {
        bf16x8 ah[4], al[4];
#pragma unroll
        for (int m = 0; m < 4; ++m) unpack8(rs[m][ks2 * 2], rs[m][ks2 * 2 + 1], ah[m], al[m]);
        mfma_ks(w1 + (size_t)(2 + ks2) * 4096, l, ah, al, acc);
    }
    // ---- process receiver chunk (ks 4,5) ----
#pragma unroll
    for (int ks2 = 0; ks2 < 2; ++ks2) {
        bf16x8 ah[4], al[4];
#pragma unroll
        for (int m = 0; m < 4; ++m) unpack8(rr[m][ks2 * 2], rr[m][ks2 * 2 + 1], ah[m], al[m]);
        mfma_ks(w1 + (size_t)(4 + ks2) * 4096, l, ah, al, acc);
    }

    // ---- ReLU + h -> LDS (per-wave private, XOR-swizzled 16B slots) ----
#pragma unroll
    for (int m = 0; m < 4; ++m) {
        char* hh = (char*)&HB[w][m][0][0];
        char* hl = (char*)&HB[w][m][1][0];
#pragma unroll
        for (int tt = 0; tt < 4; ++tt)
#pragma unroll
            for (int r = 0; r < 4; ++r) {
                int row = (kq << 2) + r;
                int col = (tt << 4) + lm;
                float hv = fmaxf(acc[m][tt][r], 0.f);
                ushort16 hi = f2bf(hv);
                ushort16 lo = f2bf(hv - bf2f(hi));
                int boff = (row << 7) + ((((col >> 3) ^ (row & 7)) & 7) << 4) + ((col & 7) << 1);
                *(unsigned short*)(hh + boff) = hi;
                *(unsigned short*)(hl + boff) = lo;
            }
    }

    // ---- GEMM2 (K=64, 2 k-steps) ----
    f32x4 acc2[4][4];
#pragma unroll
    for (int tt = 0; tt < 4; ++tt) {
        float b = b2[tt * 16 + lm];
#pragma unroll
        for (int m = 0; m < 4; ++m) { acc2[m][tt][0] = b; acc2[m][tt][1] = b; acc2[m][tt][2] = b; acc2[m][tt][3] = b; }
    }
#pragma unroll
    for (int ks = 0; ks < 2; ++ks) {
        bf16x8 ah[4], al[4];
#pragma unroll
        for (int m = 0; m < 4; ++m) {
            int boff = (lm << 7) + ((((kq + ks * 4) ^ (lm & 7)) & 7) << 4);
            ah[m] = *(const bf16x8*)((char*)&HB[w][m][0][0] + boff);
            al[m] = *(const bf16x8*)((char*)&HB[w][m][1][0] + boff);
        }
        mfma_ks(w2 + (size_t)ks * 4096, l, ah, al, acc2);
    }

    // ---- agg_e partials ----
#pragma unroll
    for (int tt = 0; tt < 4; ++tt) {
        float s = 0.f;
#pragma unroll
        for (int m = 0; m < 4; ++m)
#pragma unroll
            for (int r = 0; r < 4; ++r) {
                int rowg = base + (m << 4) + (kq << 2) + r;
                if (rowg < E) s += acc2[m][tt][r];
            }
        s += __shfl_xor(s, 16, 64);
        s += __shfl_xor(s, 32, 64);
        if (l < 16) PS[w][tt * 16 + l] = s;
    }

    // ---- C writeback via per-wave swizzled fp32 staging ----
    char* CW = (char*)&HB[w][0][0][0];  // 16 KB per wave
#pragma unroll
    for (int m = 0; m < 4; ++m)
#pragma unroll
        for (int tt = 0; tt < 4; ++tt)
#pragma unroll
            for (int r = 0; r < 4; ++r) {
                int row = (kq << 2) + r;
                int col = (tt << 4) + lm;
                int boff = (row << 8) + ((((col >> 2) ^ (row & 15)) & 15) << 4) + ((col & 3) << 2);
                *(float*)(CW + m * 4096 + boff) = acc2[m][tt][r];
            }
#pragma unroll
    for (int m = 0; m < 4; ++m) {
        int rowg = base + (m << 4) + lm;
        float4* dst = (float4*)(edges_out + (size_t)rowg * DD);
#pragma unroll
        for (int j = 0; j < 4; ++j) {
            int fc = kq + (j << 2);
            int boff = (lm << 8) + (((fc ^ (lm & 15)) & 15) << 4);
            float4 v = *(float4*)(CW + m * 4096 + boff);
            if (rowg < E) dst[fc] = v;
        }
    }

    __syncthreads();
    if (t < 64) {
        float s = PS[0][t] + PS[1][t] + PS[2][t] + PS[3][t];
        atomicAdd(agg_e + t, s);
    }
}

// ======================= node update: 256 nodes/block, 64/wave =========================
__global__ __launch_bounds__(256, 2) void node_kernel_mfma(
    const uint32* __restrict__ nodes_pk, const float* __restrict__ received,
    const unsigned short* __restrict__ w1, const float* __restrict__ b1,
    const unsigned short* __restrict__ w2, const float* __restrict__ b2,
    float* __restrict__ nodes_out, float* __restrict__ agg_n, int N)
{
    __shared__ unsigned short HB[4][4][2][1024];
    __shared__ float PS[4][64];

    const int t = threadIdx.x;
    const int w = t >> 6, l = t & 63;
    const int lm = l & 15, kq = l >> 4;
    const int base = (blockIdx.x << 8) + (w << 6);

    int gi[4];
#pragma unroll
    for (int m = 0; m < 4; ++m) gi[m] = min(base + (m << 4) + lm, N - 1);

    // issue both chunks' raws
    uint4 rn[4][4];
#pragma unroll
    for (int m = 0; m < 4; ++m) {
        const uint32* p = nodes_pk + (size_t)gi[m] * DD + kq * 8;
        rn[m][0] = *(const uint4*)(p);
        rn[m][1] = *(const uint4*)(p + 4);
        rn[m][2] = *(const uint4*)(p + 32);
        rn[m][3] = *(const uint4*)(p + 36);
    }
    float4 rc[4][4];
#pragma unroll
    for (int m = 0; m < 4; ++m) {
        const float* p = received + (size_t)gi[m] * DD + kq * 8;
        rc[m][0] = *(const float4*)(p);
        rc[m][1] = *(const float4*)(p + 4);
        rc[m][2] = *(const float4*)(p + 32);
        rc[m][3] = *(const float4*)(p + 36);
    }

    f32x4 acc[4][4];
#pragma unroll
    for (int tt = 0; tt < 4; ++tt) {
        float b = b1[tt * 16 + lm];
#pragma unroll
        for (int m = 0; m < 4; ++m) { acc[m][tt][0] = b; acc[m][tt][1] = b; acc[m][tt][2] = b; acc[m][tt][3] = b; }
    }

    // chunk0: nodes (ks 0,1)
#pragma unroll
    for (int ks2 = 0; ks2 < 2; ++ks2) {
        bf16x8 ah[4], al[4];
#pragma unroll
        for (int m = 0; m < 4; ++m) unpack8(rn[m][ks2 * 2], rn[m][ks2 * 2 + 1], ah[m], al[m]);
        mfma_ks(w1 + (size_t)ks2 * 4096, l, ah, al, acc);
    }
    // chunk1: received (ks 2,3)
#pragma unroll
    for (int ks2 = 0; ks2 < 2; ++ks2) {
        bf16x8 ah[4], al[4];
#pragma unroll
        for (int m = 0; m < 4; ++m) split8f(rc[m][ks2 * 2], rc[m][ks2 * 2 + 1], ah[m], al[m]);
        mfma_ks(w1 + (size_t)(2 + ks2) * 4096, l, ah, al, acc);
    }

    // ReLU + h -> LDS
#pragma unroll
    for (int m = 0; m < 4; ++m) {
        char* hh = (char*)&HB[w][m][0][0];
        char* hl = (char*)&HB[w][m][1][0];
#pragma unroll
        for (int tt = 0; tt < 4; ++tt)
#pragma unroll
            for (int r = 0; r < 4; ++r) {
                int row = (kq << 2) + r;
                int col = (tt << 4) + lm;
                float hv = fmaxf(acc[m][tt][r], 0.f);
                ushort16 hi = f2bf(hv);
                ushort16 lo = f2bf(hv - bf2f(hi));
                int boff = (row << 7) + ((((col >> 3) ^ (row & 7)) & 7) << 4) + ((col & 7) << 1);
                *(unsigned short*)(hh + boff) = hi;
                *(unsigned short*)(hl + boff) = lo;
            }
    }

    f32x4 acc2[4][4];
#pragma unroll
    for (int tt = 0; tt < 4; ++tt) {
        float b = b2[tt * 16 + lm];
#pragma unroll
        for (int m = 0; m < 4; ++m) { acc2[m][tt][0] = b; acc2[m][tt][1] = b; acc2[m][tt][2] = b; acc2[m][tt][3] = b; }
    }
#pragma unroll
    for (int ks = 0; ks < 2; ++ks) {
        bf16x8 ah[4], al[4];
#pragma unroll
        for (int m = 0; m < 4; ++m) {
            int boff = (lm << 7) + ((((kq + ks * 4) ^ (lm & 7)) & 7) << 4);
            ah[m] = *(const bf16x8*)((char*)&HB[w][m][0][0] + boff);
            al[m] = *(const bf16x8*)((char*)&HB[w][m][1][0] + boff);
        }
        mfma_ks(w2 + (size_t)ks * 4096, l, ah, al, acc2);
    }

#pragma unroll
    for (int tt = 0; tt < 4; ++tt) {
        float s = 0.f;
#pragma unroll
        for (int m = 0; m < 4; ++m)
#pragma unroll
            for (int r = 0; r < 4; ++r) {
                int rowg = base + (m << 4) + (kq << 2) + r;
                if (rowg < N) s += acc2[m][tt][r];
            }
        s += __shfl_xor(s, 16, 64);
        s += __shfl_xor(s, 32, 64);
        if (l < 16) PS[w][tt * 16 + l] = s;
    }

    char* CW = (char*)&HB[w][0][0][0];
#pragma unroll
    for (int m = 0; m < 4; ++m)
#pragma unroll
        for (int tt = 0; tt < 4; ++tt)
#pragma unroll
            for (int r = 0; r < 4; ++r) {
                int row = (kq << 2) + r;
                int col = (tt << 4) + lm;
                int boff = (row << 8) + ((((col >> 2) ^ (row & 15)) & 15) << 4) + ((col & 3) << 2);
                *(float*)(CW + m * 4096 + boff) = acc2[m][tt][r];
            }
#pragma unroll
    for (int m = 0; m < 4; ++m) {
        int rowg = base + (m << 4) + lm;
        float4* dst = (float4*)(nodes_out + (size_t)rowg * DD);
#pragma unroll
        for (int j = 0; j < 4; ++j) {
            int fc = kq + (j << 2);
            int boff = (lm << 8) + (((fc ^ (lm & 15)) & 15) << 4);
            float4 v = *(float4*)(CW + m * 4096 + boff);
            if (rowg < N) dst[fc] = v;
        }
    }

    __syncthreads();
    if (t < 64) {
        float s = PS[0][t] + PS[1][t] + PS[2][t] + PS[3][t];
        atomicAdd(agg_n + t, s);
    }
}

// ---------------- global update (tiny) ----------------
__global__ void global_kernel(const float* __restrict__ agg_n, const float* __restrict__ agg_e,
                              const float* __restrict__ g_in,
                              const float* __restrict__ Wg1, const float* __restrict__ bg1,
                              const float* __restrict__ Wg2, const float* __restrict__ bg2,
                              float* __restrict__ g_out)
{
    __shared__ float h[64];
    int j = threadIdx.x;  // 64 threads
    float a = bg1[j];
    for (int k = 0; k < DD; ++k) a = fmaf(agg_n[k], Wg1[k * DD + j], a);
    for (int k = 0; k < DD; ++k) a = fmaf(agg_e[k], Wg1[(64 + k) * DD + j], a);
    for (int k = 0; k < DD; ++k) a = fmaf(g_in[k],  Wg1[(128 + k) * DD + j], a);
    h[j] = fmaxf(a, 0.f);
    __syncthreads();
    float o = bg2[j];
    for (int k = 0; k < DD; ++k) o = fmaf(h[k], Wg2[k * DD + j], o);
    g_out[j] = o;
}

extern "C" void kernel_launch(void* const* d_in, const int* in_sizes, int n_in,
                              void* d_out, int out_size, void* d_ws, size_t ws_size,
                              hipStream_t stream) {
    const float* nodes0 = (const float*)d_in[0];
    const float* edges0 = (const float*)d_in[1];
    const float* g0     = (const float*)d_in[2];
    const int* senders   = (const int*)d_in[3];
    const int* receivers = (const int*)d_in[4];
    const float* We1 = (const float*)d_in[5];
    const float* be1 = (const float*)d_in[6];
    const float* We2 = (const float*)d_in[7];
    const float* be2 = (const float*)d_in[8];
    const float* Wn1 = (const float*)d_in[9];
    const float* bn1 = (const float*)d_in[10];
    const float* Wn2 = (const float*)d_in[11];
    const float* bn2 = (const float*)d_in[12];
    const float* Wg1 = (const float*)d_in[13];
    const float* bg1 = (const float*)d_in[14];
    const float* Wg2 = (const float*)d_in[15];
    const float* bg2 = (const float*)d_in[16];

    const int N = in_sizes[0] / DD;
    const int E = in_sizes[1] / DD;

    float* out_nodes = (float*)d_out;
    float* out_edges = out_nodes + (size_t)N * DD;
    float* out_g     = out_edges + (size_t)E * DD;

    float* ws = (float*)d_ws;
    float* received = ws;                              // N*64 floats
    float* aggs = received + (size_t)N * DD;           // 512 floats
    float* agg_n = aggs;          // 64
    float* agg_e = aggs + 64;     // 64
    float* b1e   = aggs + 128;    // 64
    float* b1n   = aggs + 192;    // 64
    float* g1    = aggs + 256;    // 64
    float* g2    = aggs + 320;    // 64
    int* counts = (int*)(aggs + 512);                  // N
    int* offs   = counts + N;                          // N+4
    int* cursor = offs + N + 4;                        // N
    int* perm   = cursor + N;                          // E
    uint32* nodes_pk = (uint32*)(perm + E);            // N*64
    unsigned short* we1p = (unsigned short*)(nodes_pk + (size_t)N * DD);  // 24576
    unsigned short* we2p = we1p + 24576;                                  // 8192
    unsigned short* wn1p = we2p + 8192;                                   // 16384
    unsigned short* wn2p = wn1p + 16384;                                  // 8192

    const int eblocks = (E + 255) / 256;
    const int nblocks = (N + 255) / 256;

    // ---- one-time: CSR build + weight split/swizzle ----
    zero_counts_kernel<<<(N + 255) / 256, 256, 0, stream>>>(counts, N);
    hist_kernel<<<(E + 255) / 256, 256, 0, stream>>>(receivers, counts, E);
    scan_kernel<<<1, 1024, 0, stream>>>(counts, offs, cursor, N);
    scatter_kernel<<<(E + 255) / 256, 256, 0, stream>>>(receivers, cursor, perm, E);
    prep_weights_kernel<<<48, 256, 0, stream>>>(We1, We2, Wn1, Wn2, we1p, we2p, wn1p, wn2p);

    for (int s = 0; s < 3; ++s) {
        const float* nsrc = (s == 0) ? nodes0 : out_nodes;
        const float* esrc = (s == 0) ? edges0 : out_edges;
        const float* gin  = (s == 0) ? g0 : ((s == 1) ? g1 : g2);
        float* gout       = (s == 2) ? out_g : ((s == 0) ? g1 : g2);

        hipMemsetAsync(aggs, 0, 128 * sizeof(float), stream);
        prep_bias_kernel<<<1, 64, 0, stream>>>(gin, We1, be1, Wn1, bn1, b1e, b1n);
        prep_nodes_kernel<<<(N * DD + 255) / 256, 256, 0, stream>>>(nsrc, nodes_pk, N * DD);
        edge_kernel_mfma<<<eblocks, 256, 0, stream>>>(esrc, nodes_pk, senders, receivers,
                                                      we1p, b1e, we2p, be2,
                                                      out_edges, agg_e, E);
        gather_kernel<<<(N + 3) / 4, 256, 0, stream>>>(out_edges, offs, perm, received, N);
        node_kernel_mfma<<<nblocks, 256, 0, stream>>>(nodes_pk, received, wn1p, b1n, wn2p, bn2,
                                                      out_nodes, agg_n, N);
        global_kernel<<<1, 64, 0, stream>>>(agg_n, agg_e, gin, Wg1, bg1, Wg2, bg2, gout);
    }
}

// Round 5
// 1991.533 us; speedup vs baseline: 3.1849x; 1.1602x over previous
//
#include <hip/hip_runtime.h>

#define DD 64
typedef unsigned int uint32;
typedef unsigned short ushort16;
typedef short bf16x8 __attribute__((ext_vector_type(8)));
typedef float f32x4 __attribute__((ext_vector_type(4)));

__device__ __forceinline__ ushort16 f2bf(float x) {
    uint32 u = __float_as_uint(x);
    uint32 r = (u + 0x7FFFu + ((u >> 16) & 1u)) >> 16;
    return (ushort16)r;
}
__device__ __forceinline__ float bf2f(ushort16 h) {
    return __uint_as_float(((uint32)h) << 16);
}

__device__ __forceinline__ void split8f(const float4& a, const float4& b, bf16x8& ah, bf16x8& al) {
    float xs[8] = {a.x, a.y, a.z, a.w, b.x, b.y, b.z, b.w};
#pragma unroll
    for (int i = 0; i < 8; ++i) {
        ushort16 hi = f2bf(xs[i]);
        ah[i] = (short)hi;
        al[i] = (short)f2bf(xs[i] - bf2f(hi));
    }
}
__device__ __forceinline__ void unpack8(const uint4& a, const uint4& b, bf16x8& ah, bf16x8& al) {
    uint32 us[8] = {a.x, a.y, a.z, a.w, b.x, b.y, b.z, b.w};
#pragma unroll
    for (int i = 0; i < 8; ++i) {
        ah[i] = (short)(us[i] >> 16);
        al[i] = (short)(us[i] & 0xFFFFu);
    }
}

// 1 k-step (K=32) of split-bf16 MFMA over 4 m-tiles x 4 n-tiles
__device__ __forceinline__ void mfma_ks(const unsigned short* __restrict__ wks, int l,
                                        const bf16x8* ah, const bf16x8* al, f32x4 (*acc)[4]) {
#pragma unroll
    for (int tt = 0; tt < 4; ++tt) {
        bf16x8 bh = *(const bf16x8*)(wks + ((size_t)(tt * 2 + 0) * 64 + l) * 8);
        bf16x8 bl = *(const bf16x8*)(wks + ((size_t)(tt * 2 + 1) * 64 + l) * 8);
#pragma unroll
        for (int m = 0; m < 4; ++m) {
            acc[m][tt] = __builtin_amdgcn_mfma_f32_16x16x32_bf16(ah[m], bh, acc[m][tt], 0, 0, 0);
            acc[m][tt] = __builtin_amdgcn_mfma_f32_16x16x32_bf16(ah[m], bl, acc[m][tt], 0, 0, 0);
            acc[m][tt] = __builtin_amdgcn_mfma_f32_16x16x32_bf16(al[m], bh, acc[m][tt], 0, 0, 0);
        }
    }
}

// single-m variant
__device__ __forceinline__ void mfma_ks1(const unsigned short* __restrict__ wks, int l,
                                         bf16x8 ah, bf16x8 al, f32x4* acc) {
#pragma unroll
    for (int tt = 0; tt < 4; ++tt) {
        bf16x8 bh = *(const bf16x8*)(wks + ((size_t)(tt * 2 + 0) * 64 + l) * 8);
        bf16x8 bl = *(const bf16x8*)(wks + ((size_t)(tt * 2 + 1) * 64 + l) * 8);
        acc[tt] = __builtin_amdgcn_mfma_f32_16x16x32_bf16(ah, bh, acc[tt], 0, 0, 0);
        acc[tt] = __builtin_amdgcn_mfma_f32_16x16x32_bf16(ah, bl, acc[tt], 0, 0, 0);
        acc[tt] = __builtin_amdgcn_mfma_f32_16x16x32_bf16(al, bh, acc[tt], 0, 0, 0);
    }
}

// ---------------- CSR build ----------------
__global__ void zero_counts_kernel(int* __restrict__ counts, int N) {
    int i = blockIdx.x * blockDim.x + threadIdx.x;
    if (i < N) counts[i] = 0;
}

__global__ void hist_kernel(const int* __restrict__ recv, int* __restrict__ counts, int E) {
    int i = blockIdx.x * blockDim.x + threadIdx.x;
    if (i < E) atomicAdd(&counts[recv[i]], 1);
}

__global__ __launch_bounds__(1024) void scan_kernel(const int* __restrict__ counts,
                                                    int* __restrict__ offs,
                                                    int* __restrict__ cursor, int N) {
    __shared__ int sm[1024];
    __shared__ int carryS;
    int t = threadIdx.x;
    if (t == 0) carryS = 0;
    __syncthreads();
    for (int base = 0; base < N; base += 4096) {
        int idx = base + t * 4;
        int x0 = (idx + 0 < N) ? counts[idx + 0] : 0;
        int x1 = (idx + 1 < N) ? counts[idx + 1] : 0;
        int x2 = (idx + 2 < N) ? counts[idx + 2] : 0;
        int x3 = (idx + 3 < N) ? counts[idx + 3] : 0;
        int s1 = x0 + x1, s2 = s1 + x2, s3 = s2 + x3;
        sm[t] = s3;
        __syncthreads();
        for (int d = 1; d < 1024; d <<= 1) {
            int v = (t >= d) ? sm[t - d] : 0;
            __syncthreads();
            sm[t] += v;
            __syncthreads();
        }
        int excl = sm[t] - s3 + carryS;
        if (idx < N)     { offs[idx]     = excl;      cursor[idx]     = excl; }
        if (idx + 1 < N) { offs[idx + 1] = excl + x0; cursor[idx + 1] = excl + x0; }
        if (idx + 2 < N) { offs[idx + 2] = excl + s1; cursor[idx + 2] = excl + s1; }
        if (idx + 3 < N) { offs[idx + 3] = excl + s2; cursor[idx + 3] = excl + s2; }
        int chunkTotal = sm[1023];
        __syncthreads();
        if (t == 0) carryS += chunkTotal;
        __syncthreads();
    }
    if (t == 0) offs[N] = carryS;
}

__global__ void scatter_kernel(const int* __restrict__ recv, int* __restrict__ cursor,
                               int* __restrict__ perm, int E) {
    int i = blockIdx.x * blockDim.x + threadIdx.x;
    if (i < E) {
        int p = atomicAdd(&cursor[recv[i]], 1);
        perm[p] = i;
    }
}

// ---------------- prep: fold g @ W1[g-rows] into effective layer-1 biases --------------
__global__ void prep_bias_kernel(const float* __restrict__ g,
                                 const float* __restrict__ We1, const float* __restrict__ be1,
                                 const float* __restrict__ Wn1, const float* __restrict__ bn1,
                                 float* __restrict__ be1e, float* __restrict__ bn1e) {
    int j = threadIdx.x;  // 64 threads
    float a = be1[j];
    float b = bn1[j];
    for (int k = 0; k < DD; ++k) {
        float gk = g[k];
        a = fmaf(gk, We1[(192 + k) * DD + j], a);
        b = fmaf(gk, Wn1[(128 + k) * DD + j], b);
    }
    be1e[j] = a;
    bn1e[j] = b;
}

// ---------------- prep: split nodes fp32 -> packed (hi<<16)|lo bf16 pair ---------------
__global__ void prep_nodes_kernel(const float* __restrict__ src, uint32* __restrict__ dst,
                                  int total) {
    int i = blockIdx.x * blockDim.x + threadIdx.x;
    if (i < total) {
        float x = src[i];
        ushort16 hi = f2bf(x);
        ushort16 lo = f2bf(x - bf2f(hi));
        dst[i] = ((uint32)hi << 16) | (uint32)lo;
    }
}

// ---------------- prep: weights -> hi/lo bf16, pre-swizzled into B-fragment order ------
__device__ __forceinline__ void prep_pack(const float* __restrict__ W, int nks,
                                          unsigned short* __restrict__ dst, int tid) {
    if (tid < nks * 2048) {
        int i = tid & 7, lane = (tid >> 3) & 63, tt = (tid >> 9) & 3, ks = tid >> 11;
        int k = ks * 32 + (lane >> 4) * 8 + i;
        int n = tt * 16 + (lane & 15);
        float x = W[k * DD + n];
        ushort16 hi = f2bf(x);
        ushort16 lo = f2bf(x - bf2f(hi));
        dst[(((ks * 4 + tt) * 2 + 0) * 64 + lane) * 8 + i] = hi;
        dst[(((ks * 4 + tt) * 2 + 1) * 64 + lane) * 8 + i] = lo;
    }
}

__global__ void prep_weights_kernel(const float* __restrict__ We1, const float* __restrict__ We2,
                                    const float* __restrict__ Wn1, const float* __restrict__ Wn2,
                                    unsigned short* __restrict__ we1p, unsigned short* __restrict__ we2p,
                                    unsigned short* __restrict__ wn1p, unsigned short* __restrict__ wn2p) {
    int tid = blockIdx.x * blockDim.x + threadIdx.x;
    prep_pack(We1, 6, we1p, tid);
    prep_pack(We2, 2, we2p, tid);
    prep_pack(Wn1, 4, wn1p, tid);
    prep_pack(Wn2, 2, wn2p, tid);
}

// ======== edge update, receiver-sorted via perm; fused received-aggregation ==========
// 256 edges/block (perm positions), 64/wave, per-wave 4KB LDS staging reused per m-tile.
__global__ __launch_bounds__(256, 3) void edge_kernel_mfma(
    const float* __restrict__ edges_in, const uint32* __restrict__ nodes_pk,
    const int* __restrict__ senders, const int* __restrict__ receivers,
    const int* __restrict__ perm,
    const unsigned short* __restrict__ w1, const float* __restrict__ b1,
    const unsigned short* __restrict__ w2, const float* __restrict__ b2,
    float* __restrict__ edges_out, float* __restrict__ received,
    float* __restrict__ agg_e, int E)
{
    __shared__ int PE[4][64];
    __shared__ int SID[4][64];
    __shared__ int RID[4][64];
    __shared__ float PS[4][64];
    __shared__ __align__(16) char HB[4][4096];  // per-wave staging: h (2x2KB) then C (4KB)

    const int t = threadIdx.x;
    const int w = t >> 6, l = t & 63;
    const int lm = l & 15, kq = l >> 4;
    const int base = (blockIdx.x << 8) + (w << 6);

    // wave's 64 edges (perm order): indices
    {
        int pos = base + l;
        int pe = perm[min(pos, E - 1)];
        PE[w][l] = pe;
        SID[w][l] = senders[pe];
        RID[w][l] = receivers[pe];
    }

    int pe_m[4], sid_m[4], rid_m[4];
#pragma unroll
    for (int m = 0; m < 4; ++m) {
        pe_m[m]  = PE[w][(m << 4) + lm];
        sid_m[m] = SID[w][(m << 4) + lm];
        rid_m[m] = RID[w][(m << 4) + lm];
    }

    // ---- issue edges-chunk raws (gather by perm row) ----
    float4 re[4][4];
#pragma unroll
    for (int m = 0; m < 4; ++m) {
        const float* p = edges_in + (size_t)pe_m[m] * DD + kq * 8;
        re[m][0] = *(const float4*)(p);
        re[m][1] = *(const float4*)(p + 4);
        re[m][2] = *(const float4*)(p + 32);
        re[m][3] = *(const float4*)(p + 36);
    }
    // ---- issue sender-chunk raws ----
    uint4 rs[4][4];
#pragma unroll
    for (int m = 0; m < 4; ++m) {
        const uint32* p = nodes_pk + (size_t)sid_m[m] * DD + kq * 8;
        rs[m][0] = *(const uint4*)(p);
        rs[m][1] = *(const uint4*)(p + 4);
        rs[m][2] = *(const uint4*)(p + 32);
        rs[m][3] = *(const uint4*)(p + 36);
    }

    f32x4 acc[4][4];
#pragma unroll
    for (int tt = 0; tt < 4; ++tt) {
        float b = b1[tt * 16 + lm];
#pragma unroll
        for (int m = 0; m < 4; ++m) { acc[m][tt][0] = b; acc[m][tt][1] = b; acc[m][tt][2] = b; acc[m][tt][3] = b; }
    }

    // ---- process edges chunk (ks 0,1) ----
#pragma unroll
    for (int ks2 = 0; ks2 < 2; ++ks2) {
        bf16x8 ah[4], al[4];
#pragma unroll
        for (int m = 0; m < 4; ++m) split8f(re[m][ks2 * 2], re[m][ks2 * 2 + 1], ah[m], al[m]);
        mfma_ks(w1 + (size_t)ks2 * 4096, l, ah, al, acc);
    }

    // ---- issue receiver-chunk raws (sorted -> L2/L1-hot, mostly same row per tile) ----
    uint4 rr[4][4];
#pragma unroll
    for (int m = 0; m < 4; ++m) {
        const uint32* p = nodes_pk + (size_t)rid_m[m] * DD + kq * 8;
        rr[m][0] = *(const uint4*)(p);
        rr[m][1] = *(const uint4*)(p + 4);
        rr[m][2] = *(const uint4*)(p + 32);
        rr[m][3] = *(const uint4*)(p + 36);
    }

    // ---- process sender chunk (ks 2,3) ----
#pragma unroll
    for (int ks2 = 0; ks2 < 2; ++ks2) {
        bf16x8 ah[4], al[4];
#pragma unroll
        for (int m = 0; m < 4; ++m) unpack8(rs[m][ks2 * 2], rs[m][ks2 * 2 + 1], ah[m], al[m]);
        mfma_ks(w1 + (size_t)(2 + ks2) * 4096, l, ah, al, acc);
    }
    // ---- process receiver chunk (ks 4,5) ----
#pragma unroll
    for (int ks2 = 0; ks2 < 2; ++ks2) {
        bf16x8 ah[4], al[4];
#pragma unroll
        for (int m = 0; m < 4; ++m) unpack8(rr[m][ks2 * 2], rr[m][ks2 * 2 + 1], ah[m], al[m]);
        mfma_ks(w1 + (size_t)(4 + ks2) * 4096, l, ah, al, acc);
    }

    // ---- per m-tile: h->LDS, GEMM2, C stage, store + segmented received atomics ----
    float b2v[4];
#pragma unroll
    for (int tt = 0; tt < 4; ++tt) b2v[tt] = b2[tt * 16 + lm];
    float sreg[4] = {0.f, 0.f, 0.f, 0.f};
    char* hh = &HB[w][0];
    char* hl = &HB[w][2048];

#pragma unroll
    for (int m = 0; m < 4; ++m) {
        // ReLU + split h into per-wave 2KB hi/lo planes (XOR-swizzled 16B slots)
#pragma unroll
        for (int tt = 0; tt < 4; ++tt)
#pragma unroll
            for (int r = 0; r < 4; ++r) {
                int row = (kq << 2) + r;
                int col = (tt << 4) + lm;
                float hv = fmaxf(acc[m][tt][r], 0.f);
                ushort16 hi = f2bf(hv);
                ushort16 lo = f2bf(hv - bf2f(hi));
                int boff = (row << 7) + ((((col >> 3) ^ (row & 7)) & 7) << 4) + ((col & 7) << 1);
                *(unsigned short*)(hh + boff) = hi;
                *(unsigned short*)(hl + boff) = lo;
            }

        // GEMM2 for this m-tile
        f32x4 acc2[4];
#pragma unroll
        for (int tt = 0; tt < 4; ++tt) { acc2[tt][0] = b2v[tt]; acc2[tt][1] = b2v[tt]; acc2[tt][2] = b2v[tt]; acc2[tt][3] = b2v[tt]; }
#pragma unroll
        for (int ks = 0; ks < 2; ++ks) {
            int boff = (lm << 7) + ((((kq + ks * 4) ^ (lm & 7)) & 7) << 4);
            bf16x8 ah = *(const bf16x8*)(hh + boff);
            bf16x8 al = *(const bf16x8*)(hl + boff);
            mfma_ks1(w2 + (size_t)ks * 4096, l, ah, al, acc2);
        }

        // agg_e partials (guard invalid rows)
#pragma unroll
        for (int tt = 0; tt < 4; ++tt) {
#pragma unroll
            for (int r = 0; r < 4; ++r) {
                int rowp = base + (m << 4) + (kq << 2) + r;
                if (rowp < E) sreg[tt] += acc2[tt][r];
            }
        }

        // stage C fp32 (overwrites h planes; same-wave WAR handled by lgkmcnt)
#pragma unroll
        for (int tt = 0; tt < 4; ++tt)
#pragma unroll
            for (int r = 0; r < 4; ++r) {
                int row = (kq << 2) + r;
                int col = (tt << 4) + lm;
                int boff = (row << 8) + ((((col >> 2) ^ (row & 15)) & 15) << 4) + ((col & 3) << 2);
                *(float*)(&HB[w][0] + boff) = acc2[tt][r];
            }

        // coalesced row store to edges_out (original row = PE)
        {
            int rowp = base + (m << 4) + lm;
            float4* dst = (float4*)(edges_out + (size_t)pe_m[m] * DD);
#pragma unroll
            for (int j = 0; j < 4; ++j) {
                int fc = kq + (j << 2);
                int boff = (lm << 8) + (((fc ^ (lm & 15)) & 15) << 4);
                float4 v = *(float4*)(&HB[w][0] + boff);
                if (rowp < E) dst[fc] = v;
            }
        }

        // segmented sum over the tile's 16 sorted rows -> received atomics (lane = col)
        {
            float run = 0.f;
#pragma unroll
            for (int r = 0; r < 16; ++r) {
                int rowp = base + (m << 4) + r;
                if (rowp < E) {
                    int boff = (r << 8) + ((((l >> 2) ^ (r & 15)) & 15) << 4) + ((l & 3) << 2);
                    float v = *(const float*)(&HB[w][0] + boff);
                    int rid = RID[w][(m << 4) + r];
                    run += v;
                    bool flush;
                    if (r == 15) flush = true;
                    else flush = (rowp + 1 >= E) || (RID[w][(m << 4) + r + 1] != rid);
                    if (flush) {
                        atomicAdd(&received[(size_t)rid * DD + l], run);
                        run = 0.f;
                    }
                }
            }
        }
    }

    // ---- agg_e reduce ----
#pragma unroll
    for (int tt = 0; tt < 4; ++tt) {
        float s = sreg[tt];
        s += __shfl_xor(s, 16, 64);
        s += __shfl_xor(s, 32, 64);
        if (l < 16) PS[w][tt * 16 + l] = s;
    }
    __syncthreads();
    if (t < 64) {
        float s = PS[0][t] + PS[1][t] + PS[2][t] + PS[3][t];
        atomicAdd(agg_e + t, s);
    }
}

// ======================= node update: 256 nodes/block, 64/wave =========================
__global__ __launch_bounds__(256, 2) void node_kernel_mfma(
    const uint32* __restrict__ nodes_pk, const float* __restrict__ received,
    const unsigned short* __restrict__ w1, const float* __restrict__ b1,
    const unsigned short* __restrict__ w2, const float* __restrict__ b2,
    float* __restrict__ nodes_out, float* __restrict__ agg_n, int N)
{
    __shared__ unsigned short HB[4][4][2][1024];
    __shared__ float PS[4][64];

    const int t = threadIdx.x;
    const int w = t >> 6, l = t & 63;
    const int lm = l & 15, kq = l >> 4;
    const int base = (blockIdx.x << 8) + (w << 6);

    int gi[4];
#pragma unroll
    for (int m = 0; m < 4; ++m) gi[m] = min(base + (m << 4) + lm, N - 1);

    uint4 rn[4][4];
#pragma unroll
    for (int m = 0; m < 4; ++m) {
        const uint32* p = nodes_pk + (size_t)gi[m] * DD + kq * 8;
        rn[m][0] = *(const uint4*)(p);
        rn[m][1] = *(const uint4*)(p + 4);
        rn[m][2] = *(const uint4*)(p + 32);
        rn[m][3] = *(const uint4*)(p + 36);
    }
    float4 rc[4][4];
#pragma unroll
    for (int m = 0; m < 4; ++m) {
        const float* p = received + (size_t)gi[m] * DD + kq * 8;
        rc[m][0] = *(const float4*)(p);
        rc[m][1] = *(const float4*)(p + 4);
        rc[m][2] = *(const float4*)(p + 32);
        rc[m][3] = *(const float4*)(p + 36);
    }

    f32x4 acc[4][4];
#pragma unroll
    for (int tt = 0; tt < 4; ++tt) {
        float b = b1[tt * 16 + lm];
#pragma unroll
        for (int m = 0; m < 4; ++m) { acc[m][tt][0] = b; acc[m][tt][1] = b; acc[m][tt][2] = b; acc[m][tt][3] = b; }
    }

#pragma unroll
    for (int ks2 = 0; ks2 < 2; ++ks2) {
        bf16x8 ah[4], al[4];
#pragma unroll
        for (int m = 0; m < 4; ++m) unpack8(rn[m][ks2 * 2], rn[m][ks2 * 2 + 1], ah[m], al[m]);
        mfma_ks(w1 + (size_t)ks2 * 4096, l, ah, al, acc);
    }
#pragma unroll
    for (int ks2 = 0; ks2 < 2; ++ks2) {
        bf16x8 ah[4], al[4];
#pragma unroll
        for (int m = 0; m < 4; ++m) split8f(rc[m][ks2 * 2], rc[m][ks2 * 2 + 1], ah[m], al[m]);
        mfma_ks(w1 + (size_t)(2 + ks2) * 4096, l, ah, al, acc);
    }

#pragma unroll
    for (int m = 0; m < 4; ++m) {
        char* hh = (char*)&HB[w][m][0][0];
        char* hl = (char*)&HB[w][m][1][0];
#pragma unroll
        for (int tt = 0; tt < 4; ++tt)
#pragma unroll
            for (int r = 0; r < 4; ++r) {
                int row = (kq << 2) + r;
                int col = (tt << 4) + lm;
                float hv = fmaxf(acc[m][tt][r], 0.f);
                ushort16 hi = f2bf(hv);
                ushort16 lo = f2bf(hv - bf2f(hi));
                int boff = (row << 7) + ((((col >> 3) ^ (row & 7)) & 7) << 4) + ((col & 7) << 1);
                *(unsigned short*)(hh + boff) = hi;
                *(unsigned short*)(hl + boff) = lo;
            }
    }

    f32x4 acc2[4][4];
#pragma unroll
    for (int tt = 0; tt < 4; ++tt) {
        float b = b2[tt * 16 + lm];
#pragma unroll
        for (int m = 0; m < 4; ++m) { acc2[m][tt][0] = b; acc2[m][tt][1] = b; acc2[m][tt][2] = b; acc2[m][tt][3] = b; }
    }
#pragma unroll
    for (int ks = 0; ks < 2; ++ks) {
        bf16x8 ah[4], al[4];
#pragma unroll
        for (int m = 0; m < 4; ++m) {
            int boff = (lm << 7) + ((((kq + ks * 4) ^ (lm & 7)) & 7) << 4);
            ah[m] = *(const bf16x8*)((char*)&HB[w][m][0][0] + boff);
            al[m] = *(const bf16x8*)((char*)&HB[w][m][1][0] + boff);
        }
        mfma_ks(w2 + (size_t)ks * 4096, l, ah, al, acc2);
    }

#pragma unroll
    for (int tt = 0; tt < 4; ++tt) {
        float s = 0.f;
#pragma unroll
        for (int m = 0; m < 4; ++m)
#pragma unroll
            for (int r = 0; r < 4; ++r) {
                int rowg = base + (m << 4) + (kq << 2) + r;
                if (rowg < N) s += acc2[m][tt][r];
            }
        s += __shfl_xor(s, 16, 64);
        s += __shfl_xor(s, 32, 64);
        if (l < 16) PS[w][tt * 16 + l] = s;
    }

    char* CW = (char*)&HB[w][0][0][0];
#pragma unroll
    for (int m = 0; m < 4; ++m)
#pragma unroll
        for (int tt = 0; tt < 4; ++tt)
#pragma unroll
            for (int r = 0; r < 4; ++r) {
                int row = (kq << 2) + r;
                int col = (tt << 4) + lm;
                int boff = (row << 8) + ((((col >> 2) ^ (row & 15)) & 15) << 4) + ((col & 3) << 2);
                *(float*)(CW + m * 4096 + boff) = acc2[m][tt][r];
            }
#pragma unroll
    for (int m = 0; m < 4; ++m) {
        int rowg = base + (m << 4) + lm;
        float4* dst = (float4*)(nodes_out + (size_t)rowg * DD);
#pragma unroll
        for (int j = 0; j < 4; ++j) {
            int fc = kq + (j << 2);
            int boff = (lm << 8) + (((fc ^ (lm & 15)) & 15) << 4);
            float4 v = *(float4*)(CW + m * 4096 + boff);
            if (rowg < N) dst[fc] = v;
        }
    }

    __syncthreads();
    if (t < 64) {
        float s = PS[0][t] + PS[1][t] + PS[2][t] + PS[3][t];
        atomicAdd(agg_n + t, s);
    }
}

// ---------------- global update (tiny) ----------------
__global__ void global_kernel(const float* __restrict__ agg_n, const float* __restrict__ agg_e,
                              const float* __restrict__ g_in,
                              const float* __restrict__ Wg1, const float* __restrict__ bg1,
                              const float* __restrict__ Wg2, const float* __restrict__ bg2,
                              float* __restrict__ g_out)
{
    __shared__ float h[64];
    int j = threadIdx.x;  // 64 threads
    float a = bg1[j];
    for (int k = 0; k < DD; ++k) a = fmaf(agg_n[k], Wg1[k * DD + j], a);
    for (int k = 0; k < DD; ++k) a = fmaf(agg_e[k], Wg1[(64 + k) * DD + j], a);
    for (int k = 0; k < DD; ++k) a = fmaf(g_in[k],  Wg1[(128 + k) * DD + j], a);
    h[j] = fmaxf(a, 0.f);
    __syncthreads();
    float o = bg2[j];
    for (int k = 0; k < DD; ++k) o = fmaf(h[k], Wg2[k * DD + j], o);
    g_out[j] = o;
}

extern "C" void kernel_launch(void* const* d_in, const int* in_sizes, int n_in,
                              void* d_out, int out_size, void* d_ws, size_t ws_size,
                              hipStream_t stream) {
    const float* nodes0 = (const float*)d_in[0];
    const float* edges0 = (const float*)d_in[1];
    const float* g0     = (const float*)d_in[2];
    const int* senders   = (const int*)d_in[3];
    const int* receivers = (const int*)d_in[4];
    const float* We1 = (const float*)d_in[5];
    const float* be1 = (const float*)d_in[6];
    const float* We2 = (const float*)d_in[7];
    const float* be2 = (const float*)d_in[8];
    const float* Wn1 = (const float*)d_in[9];
    const float* bn1 = (const float*)d_in[10];
    const float* Wn2 = (const float*)d_in[11];
    const float* bn2 = (const float*)d_in[12];
    const float* Wg1 = (const float*)d_in[13];
    const float* bg1 = (const float*)d_in[14];
    const float* Wg2 = (const float*)d_in[15];
    const float* bg2 = (const float*)d_in[16];

    const int N = in_sizes[0] / DD;
    const int E = in_sizes[1] / DD;

    float* out_nodes = (float*)d_out;
    float* out_edges = out_nodes + (size_t)N * DD;
    float* out_g     = out_edges + (size_t)E * DD;

    float* ws = (float*)d_ws;
    float* received = ws;                              // N*64 floats
    float* aggs = received + (size_t)N * DD;           // 512 floats
    float* agg_n = aggs;          // 64
    float* agg_e = aggs + 64;     // 64
    float* b1e   = aggs + 128;    // 64
    float* b1n   = aggs + 192;    // 64
    float* g1    = aggs + 256;    // 64
    float* g2    = aggs + 320;    // 64
    int* counts = (int*)(aggs + 512);                  // N
    int* offs   = counts + N;                          // N+4
    int* cursor = offs + N + 4;                        // N
    int* perm   = cursor + N;                          // E
    uint32* nodes_pk = (uint32*)(perm + E);            // N*64
    unsigned short* we1p = (unsigned short*)(nodes_pk + (size_t)N * DD);  // 24576
    unsigned short* we2p = we1p + 24576;                                  // 8192
    unsigned short* wn1p = we2p + 8192;                                   // 16384
    unsigned short* wn2p = wn1p + 16384;                                  // 8192

    const int eblocks = (E + 255) / 256;
    const int nblocks = (N + 255) / 256;

    // ---- one-time: CSR build + weight split/swizzle ----
    zero_counts_kernel<<<(N + 255) / 256, 256, 0, stream>>>(counts, N);
    hist_kernel<<<(E + 255) / 256, 256, 0, stream>>>(receivers, counts, E);
    scan_kernel<<<1, 1024, 0, stream>>>(counts, offs, cursor, N);
    scatter_kernel<<<(E + 255) / 256, 256, 0, stream>>>(receivers, cursor, perm, E);
    prep_weights_kernel<<<48, 256, 0, stream>>>(We1, We2, Wn1, Wn2, we1p, we2p, wn1p, wn2p);

    for (int s = 0; s < 3; ++s) {
        const float* nsrc = (s == 0) ? nodes0 : out_nodes;
        const float* esrc = (s == 0) ? edges0 : out_edges;
        const float* gin  = (s == 0) ? g0 : ((s == 1) ? g1 : g2);
        float* gout       = (s == 2) ? out_g : ((s == 0) ? g1 : g2);

        // zero received + agg_n/agg_e
        hipMemsetAsync(received, 0, ((size_t)N * DD + 128) * sizeof(float), stream);
        prep_bias_kernel<<<1, 64, 0, stream>>>(gin, We1, be1, Wn1, bn1, b1e, b1n);
        prep_nodes_kernel<<<(N * DD + 255) / 256, 256, 0, stream>>>(nsrc, nodes_pk, N * DD);
        edge_kernel_mfma<<<eblocks, 256, 0, stream>>>(esrc, nodes_pk, senders, receivers, perm,
                                                      we1p, b1e, we2p, be2,
                                                      out_edges, received, agg_e, E);
        node_kernel_mfma<<<nblocks, 256, 0, stream>>>(nodes_pk, received, wn1p, b1n, wn2p, bn2,
                                                      out_nodes, agg_n, N);
        global_kernel<<<1, 64, 0, stream>>>(agg_n, agg_e, gin, Wg1, bg1, Wg2, bg2, gout);
    }
}